// Round 13
// baseline (708.522 us; speedup 1.0000x reference)
//
#include <hip/hip_runtime.h>

#define EDIM 256
#define KNN 8
#define NB 64
#define NP 512
#define NTOT (NB * NP)
#define SLAB 16
#define NSLAB (NB / SLAB)
#define SLABPTS (SLAB * NP)   // 8192

typedef short s16x8 __attribute__((ext_vector_type(8)));
typedef float f32x4 __attribute__((ext_vector_type(4)));
typedef unsigned short ushort;

__device__ __forceinline__ ushort f2b(float f) {
    unsigned u = __float_as_uint(f);
    u = (u + 0x7fffu + ((u >> 16) & 1u)) >> 16;   // RNE
    return (ushort)u;
}
__device__ __forceinline__ float b2f(ushort h) {
    return __uint_as_float(((unsigned)h) << 16);
}
__device__ __forceinline__ void split2(float x, ushort& h, ushort& l) {
    h = f2b(x);
    l = f2b(x - b2f(h));
}

// ---------------------------------------------------------------------------
// Kernel 0a: weight prep -> transposed bf16 hi/lo pairs.
// ---------------------------------------------------------------------------
__global__ __launch_bounds__(256)
void k_cvt(const float* __restrict__ gW1, const float* __restrict__ gW2,
           const float* __restrict__ g_gamma, const float* __restrict__ g_beta,
           const float* __restrict__ gb2,
           const float* __restrict__ cW2, const float* __restrict__ pW2,
           ushort* __restrict__ Wdh, ushort* __restrict__ Wdl,
           ushort* __restrict__ Wbh, ushort* __restrict__ Wbl,
           ushort* __restrict__ g2h, ushort* __restrict__ g2l,
           float* __restrict__ hb,
           ushort* __restrict__ cW2Th, ushort* __restrict__ cW2Tl,
           ushort* __restrict__ pW2Th, ushort* __restrict__ pW2Tl)
{
    const int gid = blockIdx.x * 256 + threadIdx.x;
    ushort h, l;
    if (gid < 65536) {
        const int n = gid >> 8, k = gid & 255;
        split2(gW1[k * 256 + n] - gW1[(k + 256) * 256 + n], h, l);
        Wdh[gid] = h; Wdl[gid] = l;
    } else if (gid < 131072) {
        const int i = gid - 65536, n = i >> 8, k = i & 255;
        split2(gW1[(k + 256) * 256 + n], h, l);
        Wbh[i] = h; Wbl[i] = l;
    } else if (gid < 196608) {
        const int i = gid - 131072, n = i >> 8, k = i & 255;
        split2(g_gamma[k] * gW2[k * 256 + n], h, l);
        g2h[i] = h; g2l[i] = l;
    } else if (gid < 196864) {
        const int n = gid - 196608;
        float s = gb2[n];
        for (int k = 0; k < 256; ++k) s += g_beta[k] * gW2[k * 256 + n];
        hb[n] = s;
    } else if (gid < 213248) {
        const int i = gid - 196864, n = i >> 6, k = i & 63;
        split2(cW2[k * 256 + n], h, l);
        cW2Th[i] = h; cW2Tl[i] = l;
    } else if (gid < 229632) {
        const int i = gid - 213248, n = i >> 6, k = i & 63;
        split2(pW2[k * 256 + n], h, l);
        pW2Th[i] = h; pW2Tl[i] = l;
    }
}

// ---------------------------------------------------------------------------
// Kernel 0b: fold merge GEMM into the MLP weights (linearity).
// ---------------------------------------------------------------------------
__global__ __launch_bounds__(256)
void k_fold(const float* __restrict__ cW2, const float* __restrict__ pW2,
            const float* __restrict__ cb2, const float* __restrict__ pb2,
            const float* __restrict__ mW,
            ushort* __restrict__ WcTh, ushort* __restrict__ WcTl,
            ushort* __restrict__ WpTh, ushort* __restrict__ WpTl,
            float* __restrict__ cbM, float* __restrict__ pbM)
{
    const int gid = blockIdx.x * 256 + threadIdx.x;
    ushort h, l;
    if (gid < 16384) {
        const int j = gid >> 8, n = gid & 255;
        float s = 0.f;
        for (int k = 0; k < 256; ++k) s += cW2[j * 256 + k] * mW[(256 + k) * 256 + n];
        split2(s, h, l);
        WcTh[n * 64 + j] = h; WcTl[n * 64 + j] = l;
    } else if (gid < 32768) {
        const int i = gid - 16384, j = i >> 8, n = i & 255;
        float s = 0.f;
        for (int k = 0; k < 256; ++k) s += pW2[j * 256 + k] * mW[(512 + k) * 256 + n];
        split2(s, h, l);
        WpTh[n * 64 + j] = h; WpTl[n * 64 + j] = l;
    } else if (gid < 33024) {
        const int n = gid - 32768;
        float s = 0.f;
        for (int k = 0; k < 256; ++k) s += cb2[k] * mW[(256 + k) * 256 + n];
        cbM[n] = s;
    } else if (gid < 33280) {
        const int n = gid - 33024;
        float s = 0.f;
        for (int k = 0; k < 256; ++k) s += pb2[k] * mW[(512 + k) * 256 + n];
        pbM[n] = s;
    }
}

// ---------------------------------------------------------------------------
// Kernel 0c: classMn[c] = (class_table[c] / ||class_table[c]||) @ M0.
// ---------------------------------------------------------------------------
__global__ __launch_bounds__(256)
void k_cls(const float* __restrict__ ct, const float* __restrict__ mW,
           float* __restrict__ classMn)
{
    __shared__ float ctn[256];
    __shared__ float red[4];
    const int c = blockIdx.x, t = threadIdx.x;
    const float v = ct[c * 256 + t];
    float ss = v * v;
    #pragma unroll
    for (int s = 32; s > 0; s >>= 1) ss += __shfl_down(ss, s, 64);
    if ((t & 63) == 0) red[t >> 6] = ss;
    __syncthreads();
    const float tot = red[0] + red[1] + red[2] + red[3];
    const float r = 1.f / fmaxf(sqrtf(tot), 1e-12f);
    ctn[t] = v * r;
    __syncthreads();
    float s = 0.f;
    for (int k = 0; k < 256; ++k) s += ctn[k] * mW[k * 256 + t];
    classMn[c * 256 + t] = s;
}

// ===========================================================================
// Device bodies (shared-memory passed in; math identical to round 12).
// ===========================================================================

#define EMB_SMEM_BYTES  9984
#define EDGE_SMEM_BYTES 18432

__device__ void embed_body(char* smem, int bid,
             const float* __restrict__ classMn,
             const float* __restrict__ cW1, const float* __restrict__ cb1,
             const float* __restrict__ cb2,
             const float* __restrict__ pW1, const float* __restrict__ pb1,
             const float* __restrict__ pb2,
             const float* __restrict__ mb,
             const ushort* __restrict__ cW2Th, const ushort* __restrict__ cW2Tl,
             const ushort* __restrict__ pW2Th, const ushort* __restrict__ pW2Tl,
             const ushort* __restrict__ WcTh, const ushort* __restrict__ WcTl,
             const ushort* __restrict__ WpTh, const ushort* __restrict__ WpTl,
             const float* __restrict__ cbM, const float* __restrict__ pbM,
             const float* __restrict__ positions, const float* __restrict__ colors,
             const int* __restrict__ cls, const int cstride,
             ushort* __restrict__ ehi, ushort* __restrict__ elo,
             float* __restrict__ sqn, const int pbase)
{
    ushort* Ahc = (ushort*)smem;           // 16*72
    ushort* Alc = Ahc + 1152;
    ushort* Ahp = Alc + 1152;
    ushort* Alp = Ahp + 1152;
    float* sqc  = (float*)(smem + 9216);   // [16][4]
    float* sqp_ = sqc + 64;
    float* sqe  = sqp_ + 64;

    const int t = threadIdx.x, w = t >> 6, lane = t & 63;
    const int l15 = lane & 15, quad = lane >> 4;
    const int obase = bid * 16;            // slab-local

    {
        const int o = lane >> 4;
        const int objl = w * 4 + o;
        const int gobj = pbase + obase + objl;
        const float c0 = colors[gobj * 3], c1 = colors[gobj * 3 + 1], c2 = colors[gobj * 3 + 2];
        const float q0 = positions[gobj * 3], q1 = positions[gobj * 3 + 1], q2 = positions[gobj * 3 + 2];
        const int u0 = (lane & 15) * 4;
        #pragma unroll
        for (int uu = 0; uu < 4; ++uu) {
            const int u = u0 + uu;
            const float hc = fmaxf(cb1[u] + c0 * cW1[u] + c1 * cW1[64 + u] + c2 * cW1[128 + u], 0.f);
            const float hp = fmaxf(pb1[u] + q0 * pW1[u] + q1 * pW1[64 + u] + q2 * pW1[128 + u], 0.f);
            ushort h, l;
            split2(hc, h, l); Ahc[objl * 72 + u] = h; Alc[objl * 72 + u] = l;
            split2(hp, h, l); Ahp[objl * 72 + u] = h; Alp[objl * 72 + u] = l;
        }
    }
    __syncthreads();

    f32x4 aco[4], ape[4];
    #pragma unroll
    for (int nt = 0; nt < 4; ++nt) { aco[nt] = (f32x4){0.f,0.f,0.f,0.f}; ape[nt] = (f32x4){0.f,0.f,0.f,0.f}; }

    #pragma unroll
    for (int kt = 0; kt < 2; ++kt) {
        const int ao = l15 * 72 + kt * 32 + quad * 8;
        const s16x8 ahc = *(const s16x8*)&Ahc[ao];
        const s16x8 alc = *(const s16x8*)&Alc[ao];
        const s16x8 ahp = *(const s16x8*)&Ahp[ao];
        const s16x8 alp = *(const s16x8*)&Alp[ao];
        #pragma unroll
        for (int nt = 0; nt < 4; ++nt) {
            const int n = w * 64 + nt * 16 + l15;
            const size_t bo = (size_t)n * 64 + kt * 32 + quad * 8;
            const s16x8 cbh = *(const s16x8*)(cW2Th + bo);
            const s16x8 cbl = *(const s16x8*)(cW2Tl + bo);
            const s16x8 pbh = *(const s16x8*)(pW2Th + bo);
            const s16x8 pbl = *(const s16x8*)(pW2Tl + bo);
            aco[nt] = __builtin_amdgcn_mfma_f32_16x16x32_bf16(ahc, cbh, aco[nt], 0, 0, 0);
            ape[nt] = __builtin_amdgcn_mfma_f32_16x16x32_bf16(ahp, pbh, ape[nt], 0, 0, 0);
            aco[nt] = __builtin_amdgcn_mfma_f32_16x16x32_bf16(alc, cbh, aco[nt], 0, 0, 0);
            ape[nt] = __builtin_amdgcn_mfma_f32_16x16x32_bf16(alp, pbh, ape[nt], 0, 0, 0);
            aco[nt] = __builtin_amdgcn_mfma_f32_16x16x32_bf16(ahc, cbl, aco[nt], 0, 0, 0);
            ape[nt] = __builtin_amdgcn_mfma_f32_16x16x32_bf16(ahp, pbl, ape[nt], 0, 0, 0);
        }
    }

    float sc[4] = {0.f,0.f,0.f,0.f}, sp[4] = {0.f,0.f,0.f,0.f};
    #pragma unroll
    for (int nt = 0; nt < 4; ++nt) {
        const int col = w * 64 + nt * 16 + l15;
        const float cbv = cb2[col], pbv = pb2[col];
        #pragma unroll
        for (int r = 0; r < 4; ++r) {
            const float co = aco[nt][r] + cbv;
            const float pe = ape[nt][r] + pbv;
            sc[r] += co * co;
            sp[r] += pe * pe;
        }
    }
    #pragma unroll
    for (int s = 8; s > 0; s >>= 1) {
        #pragma unroll
        for (int r = 0; r < 4; ++r) {
            sc[r] += __shfl_xor(sc[r], s, 64);
            sp[r] += __shfl_xor(sp[r], s, 64);
        }
    }
    if (l15 == 0) {
        #pragma unroll
        for (int r = 0; r < 4; ++r) { sqc[(quad * 4 + r) * 4 + w] = sc[r]; sqp_[(quad * 4 + r) * 4 + w] = sp[r]; }
    }
    __syncthreads();

    float rco[4], rpe[4];
    #pragma unroll
    for (int r = 0; r < 4; ++r) {
        const int row = quad * 4 + r;
        rco[r] = 1.f / fmaxf(sqrtf(sqc[row*4] + sqc[row*4+1] + sqc[row*4+2] + sqc[row*4+3]), 1e-12f);
        rpe[r] = 1.f / fmaxf(sqrtf(sqp_[row*4] + sqp_[row*4+1] + sqp_[row*4+2] + sqp_[row*4+3]), 1e-12f);
    }

    f32x4 ac[4], ap[4];
    #pragma unroll
    for (int nt = 0; nt < 4; ++nt) { ac[nt] = (f32x4){0.f,0.f,0.f,0.f}; ap[nt] = (f32x4){0.f,0.f,0.f,0.f}; }

    #pragma unroll
    for (int kt = 0; kt < 2; ++kt) {
        const int ao = l15 * 72 + kt * 32 + quad * 8;
        const s16x8 ahc = *(const s16x8*)&Ahc[ao];
        const s16x8 alc = *(const s16x8*)&Alc[ao];
        const s16x8 ahp = *(const s16x8*)&Ahp[ao];
        const s16x8 alp = *(const s16x8*)&Alp[ao];
        #pragma unroll
        for (int nt = 0; nt < 4; ++nt) {
            const int n = w * 64 + nt * 16 + l15;
            const size_t bo = (size_t)n * 64 + kt * 32 + quad * 8;
            const s16x8 cbh = *(const s16x8*)(WcTh + bo);
            const s16x8 cbl = *(const s16x8*)(WcTl + bo);
            const s16x8 pbh = *(const s16x8*)(WpTh + bo);
            const s16x8 pbl = *(const s16x8*)(WpTl + bo);
            ac[nt] = __builtin_amdgcn_mfma_f32_16x16x32_bf16(ahc, cbh, ac[nt], 0, 0, 0);
            ap[nt] = __builtin_amdgcn_mfma_f32_16x16x32_bf16(ahp, pbh, ap[nt], 0, 0, 0);
            ac[nt] = __builtin_amdgcn_mfma_f32_16x16x32_bf16(alc, cbh, ac[nt], 0, 0, 0);
            ap[nt] = __builtin_amdgcn_mfma_f32_16x16x32_bf16(alp, pbh, ap[nt], 0, 0, 0);
            ac[nt] = __builtin_amdgcn_mfma_f32_16x16x32_bf16(ahc, cbl, ac[nt], 0, 0, 0);
            ap[nt] = __builtin_amdgcn_mfma_f32_16x16x32_bf16(ahp, pbl, ap[nt], 0, 0, 0);
        }
    }

    int ci[4];
    #pragma unroll
    for (int r = 0; r < 4; ++r) {
        const int gobj = pbase + obase + quad * 4 + r;
        int c = cls[(size_t)gobj * cstride];
        if ((unsigned)c > 30u) c = 0;
        ci[r] = c;
    }

    float rp[4] = {0.f,0.f,0.f,0.f};
    #pragma unroll
    for (int nt = 0; nt < 4; ++nt) {
        const int col = w * 64 + nt * 16 + l15;
        const float mbv = mb[col], cbMv = cbM[col], pbMv = pbM[col];
        #pragma unroll
        for (int r = 0; r < 4; ++r) {
            const int row = quad * 4 + r;
            const float e = classMn[ci[r] * 256 + col]
                          + rco[r] * (ac[nt][r] + cbMv)
                          + rpe[r] * (ap[nt][r] + pbMv) + mbv;
            ushort h, l;
            split2(e, h, l);
            ehi[(size_t)(obase + row) * 256 + col] = h;
            elo[(size_t)(obase + row) * 256 + col] = l;
            rp[r] += e * e;
        }
    }
    #pragma unroll
    for (int s = 8; s > 0; s >>= 1) {
        #pragma unroll
        for (int r = 0; r < 4; ++r) rp[r] += __shfl_xor(rp[r], s, 64);
    }
    if (l15 == 0) {
        #pragma unroll
        for (int r = 0; r < 4; ++r) sqe[(quad * 4 + r) * 4 + w] = rp[r];
    }
    __syncthreads();
    if (t < 16) sqn[obase + t] = sqe[t*4] + sqe[t*4+1] + sqe[t*4+2] + sqe[t*4+3];
}

__device__ void edge_body(char* smem, int bid,
            const float* __restrict__ u, const float* __restrict__ v,
            const int* __restrict__ nidx,
            const ushort* __restrict__ g2h,
            const float* __restrict__ hb,
            float* __restrict__ part, const int cell0)
{
    ushort* Abuf = (ushort*)smem;               // [2][2][2304]

    const int t = threadIdx.x, w = t >> 6, lane = t & 63;
    const int l15 = lane & 15, quad = lane >> 4;

    const int xcd = bid & 7, rest = bid >> 3;   // rest 0..127
    const int celll = xcd * 2 + (rest >> 6);
    const int pl0 = celll * NP + (rest & 63) * 8;

    const int se = t >> 2, kq = t & 3;
    const int surow = pl0 + (se >> 3);
    int svrow = nidx[(size_t)surow * KNN + (se & 7)];
    if ((unsigned)svrow >= (unsigned)SLABPTS) svrow = 0;

    float4 ua, ub, va, vb;

    #define LOADR(S)                                                             \
    {                                                                            \
        const int k0 = (S) * 32 + kq * 8;                                        \
        ua = *(const float4*)(u + (size_t)surow * 256 + k0);                     \
        ub = *(const float4*)(u + (size_t)surow * 256 + k0 + 4);                 \
        va = *(const float4*)(v + (size_t)svrow * 256 + k0);                     \
        vb = *(const float4*)(v + (size_t)svrow * 256 + k0 + 4);                 \
    }
    #define SPLITW(BUF)                                                          \
    {                                                                            \
        const float sv[8] = {                                                    \
            fmaxf(ua.x + va.x, 0.f), fmaxf(ua.y + va.y, 0.f),                    \
            fmaxf(ua.z + va.z, 0.f), fmaxf(ua.w + va.w, 0.f),                    \
            fmaxf(ub.x + vb.x, 0.f), fmaxf(ub.y + vb.y, 0.f),                    \
            fmaxf(ub.z + vb.z, 0.f), fmaxf(ub.w + vb.w, 0.f)};                   \
        union { uint2 q[2]; ushort us[8]; } th, tl;                              \
        _Pragma("unroll")                                                        \
        for (int j = 0; j < 8; ++j) { split2(sv[j], th.us[j], tl.us[j]); }       \
        *(uint2*)&Abuf[(BUF) * 4608 + se * 36 + kq * 8]            = th.q[0];    \
        *(uint2*)&Abuf[(BUF) * 4608 + se * 36 + kq * 8 + 4]        = th.q[1];    \
        *(uint2*)&Abuf[(BUF) * 4608 + 2304 + se * 36 + kq * 8]     = tl.q[0];    \
        *(uint2*)&Abuf[(BUF) * 4608 + 2304 + se * 36 + kq * 8 + 4] = tl.q[1];    \
    }

    f32x4 acc[4][4];
    #pragma unroll
    for (int mt = 0; mt < 4; ++mt)
        #pragma unroll
        for (int nt = 0; nt < 4; ++nt) acc[mt][nt] = (f32x4){0.f, 0.f, 0.f, 0.f};

    LOADR(0);
    SPLITW(0);
    LOADR(1);
    for (int s = 0; s < 8; ++s) {
        __syncthreads();
        if (s < 7) {
            SPLITW((s + 1) & 1);
            if (s < 6) LOADR(s + 2);
        }

        const int k0 = s * 32 + quad * 8;
        s16x8 ah[4], al[4];
        #pragma unroll
        for (int mt = 0; mt < 4; ++mt) {
            const int ao = (s & 1) * 4608 + (mt * 16 + l15) * 36 + quad * 8;
            union { uint2 q[2]; s16x8 v8; } Th, Tl;
            Th.q[0] = *(const uint2*)&Abuf[ao];
            Th.q[1] = *(const uint2*)&Abuf[ao + 4];
            Tl.q[0] = *(const uint2*)&Abuf[ao + 2304];
            Tl.q[1] = *(const uint2*)&Abuf[ao + 2304 + 4];
            ah[mt] = Th.v8; al[mt] = Tl.v8;
        }
        #pragma unroll
        for (int nt = 0; nt < 4; ++nt) {
            const int n = w * 64 + nt * 16 + l15;
            const s16x8 bh = *(const s16x8*)(g2h + (size_t)n * 256 + k0);
            #pragma unroll
            for (int mt = 0; mt < 4; ++mt) {
                acc[mt][nt] = __builtin_amdgcn_mfma_f32_16x16x32_bf16(ah[mt], bh, acc[mt][nt], 0, 0, 0);
                acc[mt][nt] = __builtin_amdgcn_mfma_f32_16x16x32_bf16(al[mt], bh, acc[mt][nt], 0, 0, 0);
            }
        }
    }
    #undef LOADR
    #undef SPLITW

    const int cell = cell0 + celll;
    const int slot = rest & 63;
    #pragma unroll
    for (int nt = 0; nt < 4; ++nt) {
        float rm = -3.4e38f;
        #pragma unroll
        for (int mt = 0; mt < 4; ++mt)
            rm = fmaxf(rm, fmaxf(fmaxf(acc[mt][nt][0], acc[mt][nt][1]),
                                 fmaxf(acc[mt][nt][2], acc[mt][nt][3])));
        rm = fmaxf(rm, __shfl_xor(rm, 16, 64));
        rm = fmaxf(rm, __shfl_xor(rm, 32, 64));
        if (quad == 0) {
            const int col = w * 64 + nt * 16 + l15;
            part[((size_t)cell * 64 + slot) * 256 + col] = rm + hb[col];
        }
    }
}

__device__ void select_body(int bid, const float* __restrict__ dist,
                            int* __restrict__ nidx)
{
    const int wv = threadIdx.x >> 6, lane = threadIdx.x & 63;
    const int p_sl = bid * 4 + wv;
    const float* row = dist + (size_t)p_sl * NP;

    float d[8]; int q[8];
    #pragma unroll
    for (int i = 0; i < 8; ++i) { q[i] = lane + 64 * i; d[i] = row[lane + 64 * i]; }

    for (int r = 0; r < KNN; ++r) {
        float bd = d[0]; int bq = q[0];
        #pragma unroll
        for (int i = 1; i < 8; ++i)
            if (d[i] < bd || (d[i] == bd && q[i] < bq)) { bd = d[i]; bq = q[i]; }
        #pragma unroll
        for (int s = 32; s > 0; s >>= 1) {
            const float od = __shfl_down(bd, s, 64);
            const int oq = __shfl_down(bq, s, 64);
            if (od < bd || (od == bd && oq < bq)) { bd = od; bq = oq; }
        }
        const int win = __shfl(bq, 0, 64);
        if (lane == 0) nidx[(size_t)p_sl * KNN + r] = ((p_sl >> 9) << 9) | win;
        if ((win & 63) == lane) {
            const int wi = win >> 6;
            #pragma unroll
            for (int i = 0; i < 8; ++i) if (wi == i) d[i] = 3.4e38f;
        }
    }
}

__device__ void uv_body(int bid,
          const ushort* __restrict__ ehi, const ushort* __restrict__ elo,
          const ushort* __restrict__ Wdh, const ushort* __restrict__ Wbh,
          const float* __restrict__ gb1,
          float* __restrict__ u, float* __restrict__ v)
{
    const int t = threadIdx.x, w = t >> 6, lane = t & 63;
    const int l15 = lane & 15, quad = lane >> 4;
    const int isV = bid >> 8;
    const int m0 = (bid & 255) * 32;
    const ushort* Wh = isV ? Wbh : Wdh;
    float* out = isV ? v : u;
    const int mt = w & 1, ch = w >> 1;

    const size_t arow = (size_t)(m0 + mt * 16 + l15) * 256 + quad * 8;

    f32x4 acc[8];
    #pragma unroll
    for (int nt = 0; nt < 8; ++nt) acc[nt] = (f32x4){0.f, 0.f, 0.f, 0.f};

    #pragma unroll
    for (int s = 0; s < 8; ++s) {
        const s16x8 ah = *(const s16x8*)(ehi + arow + s * 32);
        const s16x8 al = *(const s16x8*)(elo + arow + s * 32);
        #pragma unroll
        for (int nt = 0; nt < 8; ++nt) {
            const int n = (ch * 8 + nt) * 16 + l15;
            const size_t bo = (size_t)n * 256 + s * 32 + quad * 8;
            const s16x8 bh = *(const s16x8*)(Wh + bo);
            acc[nt] = __builtin_amdgcn_mfma_f32_16x16x32_bf16(ah, bh, acc[nt], 0, 0, 0);
            acc[nt] = __builtin_amdgcn_mfma_f32_16x16x32_bf16(al, bh, acc[nt], 0, 0, 0);
        }
    }

    #pragma unroll
    for (int nt = 0; nt < 8; ++nt) {
        const int col = (ch * 8 + nt) * 16 + l15;
        const float bias = isV ? 0.f : gb1[col];
        #pragma unroll
        for (int r = 0; r < 4; ++r) {
            const int row = mt * 16 + quad * 4 + r;
            out[(size_t)(m0 + row) * 256 + col] = acc[nt][r] + bias;
        }
    }
}

// ===========================================================================
// Kernels
// ===========================================================================

__global__ __launch_bounds__(256)
void k_embed(const float* classMn, const float* cW1, const float* cb1,
             const float* cb2, const float* pW1, const float* pb1,
             const float* pb2, const float* mb,
             const ushort* cW2Th, const ushort* cW2Tl,
             const ushort* pW2Th, const ushort* pW2Tl,
             const ushort* WcTh, const ushort* WcTl,
             const ushort* WpTh, const ushort* WpTl,
             const float* cbM, const float* pbM,
             const float* positions, const float* colors,
             const int* cls, const int cstride,
             ushort* ehi, ushort* elo, float* sqn, const int pbase)
{
    __shared__ __align__(16) char smem[EMB_SMEM_BYTES];
    embed_body(smem, blockIdx.x, classMn, cW1, cb1, cb2, pW1, pb1, pb2, mb,
               cW2Th, cW2Tl, pW2Th, pW2Tl, WcTh, WcTl, WpTh, WpTl, cbM, pbM,
               positions, colors, cls, cstride, ehi, elo, sqn, pbase);
}

__global__ __launch_bounds__(256)
void k_edge(const float* u, const float* v, const int* nidx,
            const ushort* g2h, const float* hb, float* part, const int cell0)
{
    __shared__ __align__(16) char smem[EDGE_SMEM_BYTES];
    edge_body(smem, blockIdx.x, u, v, nidx, g2h, hb, part, cell0);
}

// embed(slab s) || edge(slab s-1): disjoint data, one launch.
__global__ __launch_bounds__(256)
void k_emb_edge(const float* classMn, const float* cW1, const float* cb1,
                const float* cb2, const float* pW1, const float* pb1,
                const float* pb2, const float* mb,
                const ushort* cW2Th, const ushort* cW2Tl,
                const ushort* pW2Th, const ushort* pW2Tl,
                const ushort* WcTh, const ushort* WcTl,
                const ushort* WpTh, const ushort* WpTl,
                const float* cbM, const float* pbM,
                const float* positions, const float* colors,
                const int* cls, const int cstride,
                ushort* ehi, ushort* elo, float* sqn, const int pbase,
                const float* u, const float* v, const int* nidx,
                const ushort* g2h, const float* hb, float* part, const int cell0m1)
{
    __shared__ __align__(16) char smem[EDGE_SMEM_BYTES];
    if (blockIdx.x < SLABPTS / 16) {
        embed_body(smem, blockIdx.x, classMn, cW1, cb1, cb2, pW1, pb1, pb2, mb,
                   cW2Th, cW2Tl, pW2Th, pW2Tl, WcTh, WcTl, WpTh, WpTl, cbM, pbM,
                   positions, colors, cls, cstride, ehi, elo, sqn, pbase);
    } else {
        edge_body(smem, blockIdx.x - SLABPTS / 16, u, v, nidx, g2h, hb, part, cell0m1);
    }
}

// select(slab s) || uv(slab s): disjoint data (u no longer aliases dist).
__global__ __launch_bounds__(256)
void k_seluv(const float* dist, int* nidx,
             const ushort* ehi, const ushort* elo,
             const ushort* Wdh, const ushort* Wbh,
             const float* gb1, float* u, float* v)
{
    if (blockIdx.x < SLABPTS / 4) {
        select_body(blockIdx.x, dist, nidx);
    } else {
        uv_body(blockIdx.x - SLABPTS / 4, ehi, elo, Wdh, Wbh, gb1, u, v);
    }
}

// ---------------------------------------------------------------------------
// Kernel 2: Gram/distance via 3-pass split MFMA, 128x64 tile per block.
// (Full 3-pass kept: kNN selection fidelity.) s-loop unrolled for scheduling.
// ---------------------------------------------------------------------------
__global__ __launch_bounds__(256)
void k_gram(const ushort* __restrict__ ehi, const ushort* __restrict__ elo,
            const float* __restrict__ sqn, float* __restrict__ dist)
{
    const int t = threadIdx.x, w = t >> 6, lane = t & 63;
    const int l15 = lane & 15, quad = lane >> 4;
    const int b_local = blockIdx.x >> 5;
    const int tile = blockIdx.x & 31;
    const int p0 = (tile >> 3) * 128, q0 = (tile & 7) * 64;
    const size_t cb = (size_t)b_local * NP;

    f32x4 acc[2][4];
    #pragma unroll
    for (int sub = 0; sub < 2; ++sub)
        #pragma unroll
        for (int nt = 0; nt < 4; ++nt) acc[sub][nt] = (f32x4){0.f, 0.f, 0.f, 0.f};

    #pragma unroll
    for (int s = 0; s < 8; ++s) {
        s16x8 ah[2], al[2];
        #pragma unroll
        for (int sub = 0; sub < 2; ++sub) {
            const size_t ao = (cb + p0 + sub * 64 + 16 * w + l15) * 256 + s * 32 + quad * 8;
            ah[sub] = *(const s16x8*)(ehi + ao);
            al[sub] = *(const s16x8*)(elo + ao);
        }
        #pragma unroll
        for (int nt = 0; nt < 4; ++nt) {
            const size_t bo = (cb + q0 + nt * 16 + l15) * 256 + s * 32 + quad * 8;
            const s16x8 bh = *(const s16x8*)(ehi + bo);
            const s16x8 bl = *(const s16x8*)(elo + bo);
            #pragma unroll
            for (int sub = 0; sub < 2; ++sub) {
                acc[sub][nt] = __builtin_amdgcn_mfma_f32_16x16x32_bf16(ah[sub], bh, acc[sub][nt], 0, 0, 0);
                acc[sub][nt] = __builtin_amdgcn_mfma_f32_16x16x32_bf16(al[sub], bh, acc[sub][nt], 0, 0, 0);
                acc[sub][nt] = __builtin_amdgcn_mfma_f32_16x16x32_bf16(ah[sub], bl, acc[sub][nt], 0, 0, 0);
            }
        }
    }

    #pragma unroll
    for (int sub = 0; sub < 2; ++sub) {
        float sqp[4];
        #pragma unroll
        for (int r = 0; r < 4; ++r)
            sqp[r] = sqn[cb + p0 + sub * 64 + 16 * w + quad * 4 + r];
        #pragma unroll
        for (int nt = 0; nt < 4; ++nt) {
            const int colq = q0 + nt * 16 + l15;
            const float sq_q = sqn[cb + colq];
            #pragma unroll
            for (int r = 0; r < 4; ++r) {
                const int rowp = p0 + sub * 64 + 16 * w + quad * 4 + r;
                dist[(cb + rowp) * NP + colq] = (sqp[r] + sq_q) - 2.f * acc[sub][nt][r];
            }
        }
    }
}

// ---------------------------------------------------------------------------
// Kernel 6: reduce 64 partial maxes per cell, final MLP (f32), L2 normalize.
// ---------------------------------------------------------------------------
__global__ __launch_bounds__(256)
void k_final(const float* __restrict__ part,
             const float* __restrict__ lW1, const float* __restrict__ lb1,
             const float* __restrict__ lW2, const float* __restrict__ lb2,
             float* __restrict__ out)
{
    __shared__ float pooled[256];
    __shared__ float hid[256];
    __shared__ float red[4];

    const int b = blockIdx.x;
    const int t = threadIdx.x;

    float m = -3.4e38f;
    for (int s = 0; s < 64; ++s)
        m = fmaxf(m, part[((size_t)b * 64 + s) * 256 + t]);
    pooled[t] = m;
    __syncthreads();

    float h = lb1[t];
    for (int k = 0; k < 256; k += 4) {
        #pragma unroll
        for (int kk = 0; kk < 4; ++kk)
            h += pooled[k + kk] * lW1[(k + kk) * 256 + t];
    }
    hid[t] = fmaxf(h, 0.f);
    __syncthreads();

    float o = lb2[t];
    for (int k = 0; k < 256; k += 4) {
        #pragma unroll
        for (int kk = 0; kk < 4; ++kk)
            o += hid[k + kk] * lW2[(k + kk) * 256 + t];
    }

    float ss = o * o;
    #pragma unroll
    for (int s = 32; s > 0; s >>= 1) ss += __shfl_down(ss, s, 64);
    if ((t & 63) == 0) red[t >> 6] = ss;
    __syncthreads();
    const float tot = red[0] + red[1] + red[2] + red[3];
    const float rn = 1.f / fmaxf(sqrtf(tot), 1e-12f);
    out[b * 256 + t] = o * rn;
}

// ---------------------------------------------------------------------------
extern "C" void kernel_launch(void* const* d_in, const int* in_sizes, int n_in,
                              void* d_out, int out_size, void* d_ws, size_t ws_size,
                              hipStream_t stream)
{
    (void)n_in; (void)out_size; (void)ws_size;

    const float* class_table = (const float*)d_in[0];
    const float* cW1 = (const float*)d_in[1];
    const float* cb1 = (const float*)d_in[2];
    const float* cW2 = (const float*)d_in[3];
    const float* cb2 = (const float*)d_in[4];
    const float* pW1 = (const float*)d_in[5];
    const float* pb1 = (const float*)d_in[6];
    const float* pW2 = (const float*)d_in[7];
    const float* pb2 = (const float*)d_in[8];
    const float* mW  = (const float*)d_in[9];
    const float* mb  = (const float*)d_in[10];
    const float* gW1 = (const float*)d_in[11];
    const float* gb1 = (const float*)d_in[12];
    const float* g_gamma = (const float*)d_in[13];
    const float* g_beta  = (const float*)d_in[14];
    const float* gW2 = (const float*)d_in[15];
    const float* gb2 = (const float*)d_in[16];
    const float* lW1 = (const float*)d_in[17];
    const float* lb1 = (const float*)d_in[18];
    const float* lW2 = (const float*)d_in[19];
    const float* lb2 = (const float*)d_in[20];
    const float* positions = (const float*)d_in[21];
    const float* colors    = (const float*)d_in[22];
    const int*  cls        = (const int*)d_in[23];

    const int cstride = (in_sizes[23] == 2 * NTOT) ? 2 : 1;

    // workspace layout (bytes), peak ~47.5 MB. u is NO LONGER aliased with
    // dist (select(s) reads dist while uv(s) writes u in the same launch).
    char* base = (char*)d_ws;
    float*   part   = (float*)(base + 0);               // 4,194,304
    ushort*  Wdh    = (ushort*)(base + 4194304);
    ushort*  Wdl    = (ushort*)(base + 4325376);
    ushort*  Wbh    = (ushort*)(base + 4456448);
    ushort*  Wbl    = (ushort*)(base + 4587520);
    ushort*  g2h    = (ushort*)(base + 4718592);
    ushort*  g2l    = (ushort*)(base + 4849664);
    float*   hb     = (float*)(base + 4980736);
    ushort*  cW2Th  = (ushort*)(base + 4981760);
    ushort*  cW2Tl  = (ushort*)(base + 5014528);
    ushort*  pW2Th  = (ushort*)(base + 5047296);
    ushort*  pW2Tl  = (ushort*)(base + 5080064);
    ushort*  WcTh   = (ushort*)(base + 5112832);
    ushort*  WcTl   = (ushort*)(base + 5145600);
    ushort*  WpTh   = (ushort*)(base + 5178368);
    ushort*  WpTl   = (ushort*)(base + 5211136);
    float*   classMn= (float*)(base + 5243904);
    float*   cbM    = (float*)(base + 5275648);
    float*   pbM    = (float*)(base + 5276672);
    int*     nidx   = (int*)(base + 5277696);           // 262,144
    float*   sqn    = (float*)(base + 5539840);         // 32,768
    ushort*  ehi    = (ushort*)(base + 5572608);        // 4,194,304
    ushort*  elo    = (ushort*)(base + 9766912);        // 4,194,304
    float*   dist   = (float*)(base + 13961216);        // 16,777,216
    float*   v      = (float*)(base + 30738432);        // 8,388,608
    float*   u      = (float*)(base + 39127040);        // 8,388,608 (own buffer)
    float* out = (float*)d_out;

    k_cvt<<<897, 256, 0, stream>>>(gW1, gW2, g_gamma, g_beta, gb2, cW2, pW2,
                                   Wdh, Wdl, Wbh, Wbl, g2h, g2l, hb,
                                   cW2Th, cW2Tl, pW2Th, pW2Tl);
    k_fold<<<130, 256, 0, stream>>>(cW2, pW2, cb2, pb2, mW,
                                    WcTh, WcTl, WpTh, WpTl, cbM, pbM);
    k_cls<<<31, 256, 0, stream>>>(class_table, mW, classMn);

    for (int s = 0; s < NSLAB; ++s) {
        if (s == 0) {
            k_embed<<<SLABPTS / 16, 256, 0, stream>>>(
                classMn, cW1, cb1, cb2, pW1, pb1, pb2, mb,
                cW2Th, cW2Tl, pW2Th, pW2Tl, WcTh, WcTl, WpTh, WpTl, cbM, pbM,
                positions, colors, cls, cstride, ehi, elo, sqn, s * SLABPTS);
        } else {
            k_emb_edge<<<SLABPTS / 16 + SLABPTS / 8, 256, 0, stream>>>(
                classMn, cW1, cb1, cb2, pW1, pb1, pb2, mb,
                cW2Th, cW2Tl, pW2Th, pW2Tl, WcTh, WcTl, WpTh, WpTl, cbM, pbM,
                positions, colors, cls, cstride, ehi, elo, sqn, s * SLABPTS,
                u, v, nidx, g2h, hb, part, (s - 1) * SLAB);
        }
        k_gram<<<SLAB * 32, 256, 0, stream>>>(ehi, elo, sqn, dist);
        k_seluv<<<SLABPTS / 4 + 2 * SLABPTS / 32, 256, 0, stream>>>(
            dist, nidx, ehi, elo, Wdh, Wbh, gb1, u, v);
    }
    k_edge<<<SLABPTS / 8, 256, 0, stream>>>(u, v, nidx, g2h, hb,
                                            part, (NSLAB - 1) * SLAB);
    k_final<<<NB, 256, 0, stream>>>(part, lW1, lb1, lW2, lb2, out);
}

// Round 14
// 547.175 us; speedup vs baseline: 1.2949x; 1.2949x over previous
//
#include <hip/hip_runtime.h>

#define EDIM 256
#define KNN 8
#define NB 64
#define NP 512
#define NTOT (NB * NP)

typedef short s16x8 __attribute__((ext_vector_type(8)));
typedef float f32x4 __attribute__((ext_vector_type(4)));
typedef unsigned short ushort;

__device__ __forceinline__ ushort f2b(float f) {
    unsigned u = __float_as_uint(f);
    u = (u + 0x7fffu + ((u >> 16) & 1u)) >> 16;   // RNE
    return (ushort)u;
}
__device__ __forceinline__ float b2f(ushort h) {
    return __uint_as_float(((unsigned)h) << 16);
}
__device__ __forceinline__ void split2(float x, ushort& h, ushort& l) {
    h = f2b(x);
    l = f2b(x - b2f(h));
}

// ---------------------------------------------------------------------------
// Kernel 0a: weight prep -> transposed bf16 hi/lo pairs.
// ---------------------------------------------------------------------------
__global__ __launch_bounds__(256)
void k_cvt(const float* __restrict__ gW1, const float* __restrict__ gW2,
           const float* __restrict__ g_gamma, const float* __restrict__ g_beta,
           const float* __restrict__ gb2,
           const float* __restrict__ cW2, const float* __restrict__ pW2,
           ushort* __restrict__ Wdh, ushort* __restrict__ Wdl,
           ushort* __restrict__ Wbh, ushort* __restrict__ Wbl,
           ushort* __restrict__ g2h, ushort* __restrict__ g2l,
           float* __restrict__ hb,
           ushort* __restrict__ cW2Th, ushort* __restrict__ cW2Tl,
           ushort* __restrict__ pW2Th, ushort* __restrict__ pW2Tl)
{
    const int gid = blockIdx.x * 256 + threadIdx.x;
    ushort h, l;
    if (gid < 65536) {
        const int n = gid >> 8, k = gid & 255;
        split2(gW1[k * 256 + n] - gW1[(k + 256) * 256 + n], h, l);
        Wdh[gid] = h; Wdl[gid] = l;
    } else if (gid < 131072) {
        const int i = gid - 65536, n = i >> 8, k = i & 255;
        split2(gW1[(k + 256) * 256 + n], h, l);
        Wbh[i] = h; Wbl[i] = l;
    } else if (gid < 196608) {
        const int i = gid - 131072, n = i >> 8, k = i & 255;
        split2(g_gamma[k] * gW2[k * 256 + n], h, l);
        g2h[i] = h; g2l[i] = l;
    } else if (gid < 196864) {
        const int n = gid - 196608;
        float s = gb2[n];
        for (int k = 0; k < 256; ++k) s += g_beta[k] * gW2[k * 256 + n];
        hb[n] = s;
    } else if (gid < 213248) {
        const int i = gid - 196864, n = i >> 6, k = i & 63;
        split2(cW2[k * 256 + n], h, l);
        cW2Th[i] = h; cW2Tl[i] = l;
    } else if (gid < 229632) {
        const int i = gid - 213248, n = i >> 6, k = i & 63;
        split2(pW2[k * 256 + n], h, l);
        pW2Th[i] = h; pW2Tl[i] = l;
    }
}

// ---------------------------------------------------------------------------
// Kernel 0b: fold merge GEMM into the MLP weights (linearity).
// ---------------------------------------------------------------------------
__global__ __launch_bounds__(256)
void k_fold(const float* __restrict__ cW2, const float* __restrict__ pW2,
            const float* __restrict__ cb2, const float* __restrict__ pb2,
            const float* __restrict__ mW,
            ushort* __restrict__ WcTh, ushort* __restrict__ WcTl,
            ushort* __restrict__ WpTh, ushort* __restrict__ WpTl,
            float* __restrict__ cbM, float* __restrict__ pbM)
{
    const int gid = blockIdx.x * 256 + threadIdx.x;
    ushort h, l;
    if (gid < 16384) {
        const int j = gid >> 8, n = gid & 255;
        float s = 0.f;
        for (int k = 0; k < 256; ++k) s += cW2[j * 256 + k] * mW[(256 + k) * 256 + n];
        split2(s, h, l);
        WcTh[n * 64 + j] = h; WcTl[n * 64 + j] = l;
    } else if (gid < 32768) {
        const int i = gid - 16384, j = i >> 8, n = i & 255;
        float s = 0.f;
        for (int k = 0; k < 256; ++k) s += pW2[j * 256 + k] * mW[(512 + k) * 256 + n];
        split2(s, h, l);
        WpTh[n * 64 + j] = h; WpTl[n * 64 + j] = l;
    } else if (gid < 33024) {
        const int n = gid - 32768;
        float s = 0.f;
        for (int k = 0; k < 256; ++k) s += cb2[k] * mW[(256 + k) * 256 + n];
        cbM[n] = s;
    } else if (gid < 33280) {
        const int n = gid - 33024;
        float s = 0.f;
        for (int k = 0; k < 256; ++k) s += pb2[k] * mW[(512 + k) * 256 + n];
        pbM[n] = s;
    }
}

// ---------------------------------------------------------------------------
// Kernel 0c: classMn[c] = (class_table[c] / ||class_table[c]||) @ M0.
// ---------------------------------------------------------------------------
__global__ __launch_bounds__(256)
void k_cls(const float* __restrict__ ct, const float* __restrict__ mW,
           float* __restrict__ classMn)
{
    __shared__ float ctn[256];
    __shared__ float red[4];
    const int c = blockIdx.x, t = threadIdx.x;
    const float v = ct[c * 256 + t];
    float ss = v * v;
    #pragma unroll
    for (int s = 32; s > 0; s >>= 1) ss += __shfl_down(ss, s, 64);
    if ((t & 63) == 0) red[t >> 6] = ss;
    __syncthreads();
    const float tot = red[0] + red[1] + red[2] + red[3];
    const float r = 1.f / fmaxf(sqrtf(tot), 1e-12f);
    ctn[t] = v * r;
    __syncthreads();
    float s = 0.f;
    for (int k = 0; k < 256; ++k) s += ctn[k] * mW[k * 256 + t];
    classMn[c * 256 + t] = s;
}

// ---------------------------------------------------------------------------
// Kernel 1: embeddings via folded GEMMs. 16 obj/block, full problem (2048).
// ---------------------------------------------------------------------------
__global__ __launch_bounds__(256)
void k_embed(const float* __restrict__ classMn,
             const float* __restrict__ cW1, const float* __restrict__ cb1,
             const float* __restrict__ cb2,
             const float* __restrict__ pW1, const float* __restrict__ pb1,
             const float* __restrict__ pb2,
             const float* __restrict__ mb,
             const ushort* __restrict__ cW2Th, const ushort* __restrict__ cW2Tl,
             const ushort* __restrict__ pW2Th, const ushort* __restrict__ pW2Tl,
             const ushort* __restrict__ WcTh, const ushort* __restrict__ WcTl,
             const ushort* __restrict__ WpTh, const ushort* __restrict__ WpTl,
             const float* __restrict__ cbM, const float* __restrict__ pbM,
             const float* __restrict__ positions, const float* __restrict__ colors,
             const int* __restrict__ cls, const int cstride,
             ushort* __restrict__ ehi, ushort* __restrict__ elo,
             float* __restrict__ sqn)
{
    __shared__ __align__(16) ushort Ahc[16 * 72];
    __shared__ __align__(16) ushort Alc[16 * 72];
    __shared__ __align__(16) ushort Ahp[16 * 72];
    __shared__ __align__(16) ushort Alp[16 * 72];
    __shared__ float sqc[16][4], sqp_[16][4], sqe[16][4];

    const int t = threadIdx.x, w = t >> 6, lane = t & 63;
    const int l15 = lane & 15, quad = lane >> 4;
    const int obase = blockIdx.x * 16;

    {
        const int o = lane >> 4;
        const int objl = w * 4 + o;
        const int gobj = obase + objl;
        const float c0 = colors[gobj * 3], c1 = colors[gobj * 3 + 1], c2 = colors[gobj * 3 + 2];
        const float q0 = positions[gobj * 3], q1 = positions[gobj * 3 + 1], q2 = positions[gobj * 3 + 2];
        const int u0 = (lane & 15) * 4;
        #pragma unroll
        for (int uu = 0; uu < 4; ++uu) {
            const int u = u0 + uu;
            const float hc = fmaxf(cb1[u] + c0 * cW1[u] + c1 * cW1[64 + u] + c2 * cW1[128 + u], 0.f);
            const float hp = fmaxf(pb1[u] + q0 * pW1[u] + q1 * pW1[64 + u] + q2 * pW1[128 + u], 0.f);
            ushort h, l;
            split2(hc, h, l); Ahc[objl * 72 + u] = h; Alc[objl * 72 + u] = l;
            split2(hp, h, l); Ahp[objl * 72 + u] = h; Alp[objl * 72 + u] = l;
        }
    }
    __syncthreads();

    f32x4 aco[4], ape[4];
    #pragma unroll
    for (int nt = 0; nt < 4; ++nt) { aco[nt] = (f32x4){0.f,0.f,0.f,0.f}; ape[nt] = (f32x4){0.f,0.f,0.f,0.f}; }

    #pragma unroll
    for (int kt = 0; kt < 2; ++kt) {
        const int ao = l15 * 72 + kt * 32 + quad * 8;
        const s16x8 ahc = *(const s16x8*)&Ahc[ao];
        const s16x8 alc = *(const s16x8*)&Alc[ao];
        const s16x8 ahp = *(const s16x8*)&Ahp[ao];
        const s16x8 alp = *(const s16x8*)&Alp[ao];
        #pragma unroll
        for (int nt = 0; nt < 4; ++nt) {
            const int n = w * 64 + nt * 16 + l15;
            const size_t bo = (size_t)n * 64 + kt * 32 + quad * 8;
            const s16x8 cbh = *(const s16x8*)(cW2Th + bo);
            const s16x8 cbl = *(const s16x8*)(cW2Tl + bo);
            const s16x8 pbh = *(const s16x8*)(pW2Th + bo);
            const s16x8 pbl = *(const s16x8*)(pW2Tl + bo);
            aco[nt] = __builtin_amdgcn_mfma_f32_16x16x32_bf16(ahc, cbh, aco[nt], 0, 0, 0);
            ape[nt] = __builtin_amdgcn_mfma_f32_16x16x32_bf16(ahp, pbh, ape[nt], 0, 0, 0);
            aco[nt] = __builtin_amdgcn_mfma_f32_16x16x32_bf16(alc, cbh, aco[nt], 0, 0, 0);
            ape[nt] = __builtin_amdgcn_mfma_f32_16x16x32_bf16(alp, pbh, ape[nt], 0, 0, 0);
            aco[nt] = __builtin_amdgcn_mfma_f32_16x16x32_bf16(ahc, cbl, aco[nt], 0, 0, 0);
            ape[nt] = __builtin_amdgcn_mfma_f32_16x16x32_bf16(ahp, pbl, ape[nt], 0, 0, 0);
        }
    }

    float sc[4] = {0.f,0.f,0.f,0.f}, sp[4] = {0.f,0.f,0.f,0.f};
    #pragma unroll
    for (int nt = 0; nt < 4; ++nt) {
        const int col = w * 64 + nt * 16 + l15;
        const float cbv = cb2[col], pbv = pb2[col];
        #pragma unroll
        for (int r = 0; r < 4; ++r) {
            const float co = aco[nt][r] + cbv;
            const float pe = ape[nt][r] + pbv;
            sc[r] += co * co;
            sp[r] += pe * pe;
        }
    }
    #pragma unroll
    for (int s = 8; s > 0; s >>= 1) {
        #pragma unroll
        for (int r = 0; r < 4; ++r) {
            sc[r] += __shfl_xor(sc[r], s, 64);
            sp[r] += __shfl_xor(sp[r], s, 64);
        }
    }
    if (l15 == 0) {
        #pragma unroll
        for (int r = 0; r < 4; ++r) { sqc[quad * 4 + r][w] = sc[r]; sqp_[quad * 4 + r][w] = sp[r]; }
    }
    __syncthreads();

    float rco[4], rpe[4];
    #pragma unroll
    for (int r = 0; r < 4; ++r) {
        const int row = quad * 4 + r;
        rco[r] = 1.f / fmaxf(sqrtf(sqc[row][0] + sqc[row][1] + sqc[row][2] + sqc[row][3]), 1e-12f);
        rpe[r] = 1.f / fmaxf(sqrtf(sqp_[row][0] + sqp_[row][1] + sqp_[row][2] + sqp_[row][3]), 1e-12f);
    }

    f32x4 ac[4], ap[4];
    #pragma unroll
    for (int nt = 0; nt < 4; ++nt) { ac[nt] = (f32x4){0.f,0.f,0.f,0.f}; ap[nt] = (f32x4){0.f,0.f,0.f,0.f}; }

    #pragma unroll
    for (int kt = 0; kt < 2; ++kt) {
        const int ao = l15 * 72 + kt * 32 + quad * 8;
        const s16x8 ahc = *(const s16x8*)&Ahc[ao];
        const s16x8 alc = *(const s16x8*)&Alc[ao];
        const s16x8 ahp = *(const s16x8*)&Ahp[ao];
        const s16x8 alp = *(const s16x8*)&Alp[ao];
        #pragma unroll
        for (int nt = 0; nt < 4; ++nt) {
            const int n = w * 64 + nt * 16 + l15;
            const size_t bo = (size_t)n * 64 + kt * 32 + quad * 8;
            const s16x8 cbh = *(const s16x8*)(WcTh + bo);
            const s16x8 cbl = *(const s16x8*)(WcTl + bo);
            const s16x8 pbh = *(const s16x8*)(WpTh + bo);
            const s16x8 pbl = *(const s16x8*)(WpTl + bo);
            ac[nt] = __builtin_amdgcn_mfma_f32_16x16x32_bf16(ahc, cbh, ac[nt], 0, 0, 0);
            ap[nt] = __builtin_amdgcn_mfma_f32_16x16x32_bf16(ahp, pbh, ap[nt], 0, 0, 0);
            ac[nt] = __builtin_amdgcn_mfma_f32_16x16x32_bf16(alc, cbh, ac[nt], 0, 0, 0);
            ap[nt] = __builtin_amdgcn_mfma_f32_16x16x32_bf16(alp, pbh, ap[nt], 0, 0, 0);
            ac[nt] = __builtin_amdgcn_mfma_f32_16x16x32_bf16(ahc, cbl, ac[nt], 0, 0, 0);
            ap[nt] = __builtin_amdgcn_mfma_f32_16x16x32_bf16(ahp, pbl, ap[nt], 0, 0, 0);
        }
    }

    int ci[4];
    #pragma unroll
    for (int r = 0; r < 4; ++r) {
        const int gobj = obase + quad * 4 + r;
        int c = cls[(size_t)gobj * cstride];
        if ((unsigned)c > 30u) c = 0;
        ci[r] = c;
    }

    float rp[4] = {0.f,0.f,0.f,0.f};
    #pragma unroll
    for (int nt = 0; nt < 4; ++nt) {
        const int col = w * 64 + nt * 16 + l15;
        const float mbv = mb[col], cbMv = cbM[col], pbMv = pbM[col];
        #pragma unroll
        for (int r = 0; r < 4; ++r) {
            const int row = quad * 4 + r;
            const float e = classMn[ci[r] * 256 + col]
                          + rco[r] * (ac[nt][r] + cbMv)
                          + rpe[r] * (ap[nt][r] + pbMv) + mbv;
            ushort h, l;
            split2(e, h, l);
            ehi[(size_t)(obase + row) * 256 + col] = h;
            elo[(size_t)(obase + row) * 256 + col] = l;
            rp[r] += e * e;
        }
    }
    #pragma unroll
    for (int s = 8; s > 0; s >>= 1) {
        #pragma unroll
        for (int r = 0; r < 4; ++r) rp[r] += __shfl_xor(rp[r], s, 64);
    }
    if (l15 == 0) {
        #pragma unroll
        for (int r = 0; r < 4; ++r) sqe[quad * 4 + r][w] = rp[r];
    }
    __syncthreads();
    if (t < 16) sqn[obase + t] = sqe[t][0] + sqe[t][1] + sqe[t][2] + sqe[t][3];
}

// ---------------------------------------------------------------------------
// Kernel 2: Gram/distance via 3-pass split MFMA, 128x64 tile per block.
// Full problem: 64 cells x 32 tiles = 2048 blocks.
// ---------------------------------------------------------------------------
__global__ __launch_bounds__(256)
void k_gram(const ushort* __restrict__ ehi, const ushort* __restrict__ elo,
            const float* __restrict__ sqn, float* __restrict__ dist)
{
    const int t = threadIdx.x, w = t >> 6, lane = t & 63;
    const int l15 = lane & 15, quad = lane >> 4;
    const int b_local = blockIdx.x >> 5;       // 0..63
    const int tile = blockIdx.x & 31;
    const int p0 = (tile >> 3) * 128, q0 = (tile & 7) * 64;
    const size_t cb = (size_t)b_local * NP;

    f32x4 acc[2][4];
    #pragma unroll
    for (int sub = 0; sub < 2; ++sub)
        #pragma unroll
        for (int nt = 0; nt < 4; ++nt) acc[sub][nt] = (f32x4){0.f, 0.f, 0.f, 0.f};

    #pragma unroll
    for (int s = 0; s < 8; ++s) {
        s16x8 ah[2], al[2];
        #pragma unroll
        for (int sub = 0; sub < 2; ++sub) {
            const size_t ao = (cb + p0 + sub * 64 + 16 * w + l15) * 256 + s * 32 + quad * 8;
            ah[sub] = *(const s16x8*)(ehi + ao);
            al[sub] = *(const s16x8*)(elo + ao);
        }
        #pragma unroll
        for (int nt = 0; nt < 4; ++nt) {
            const size_t bo = (cb + q0 + nt * 16 + l15) * 256 + s * 32 + quad * 8;
            const s16x8 bh = *(const s16x8*)(ehi + bo);
            const s16x8 bl = *(const s16x8*)(elo + bo);
            #pragma unroll
            for (int sub = 0; sub < 2; ++sub) {
                acc[sub][nt] = __builtin_amdgcn_mfma_f32_16x16x32_bf16(ah[sub], bh, acc[sub][nt], 0, 0, 0);
                acc[sub][nt] = __builtin_amdgcn_mfma_f32_16x16x32_bf16(al[sub], bh, acc[sub][nt], 0, 0, 0);
                acc[sub][nt] = __builtin_amdgcn_mfma_f32_16x16x32_bf16(ah[sub], bl, acc[sub][nt], 0, 0, 0);
            }
        }
    }

    #pragma unroll
    for (int sub = 0; sub < 2; ++sub) {
        float sqp[4];
        #pragma unroll
        for (int r = 0; r < 4; ++r)
            sqp[r] = sqn[cb + p0 + sub * 64 + 16 * w + quad * 4 + r];
        #pragma unroll
        for (int nt = 0; nt < 4; ++nt) {
            const int colq = q0 + nt * 16 + l15;
            const float sq_q = sqn[cb + colq];
            #pragma unroll
            for (int r = 0; r < 4; ++r) {
                const int rowp = p0 + sub * 64 + 16 * w + quad * 4 + r;
                dist[(cb + rowp) * NP + colq] = (sqp[r] + sq_q) - 2.f * acc[sub][nt][r];
            }
        }
    }
}

// ---------------------------------------------------------------------------
// Kernel 3: top-8 smallest per point (ties -> lowest index). One wave/point,
// full problem (8192 blocks). Vectorized loads: lane owns cols lane*8..+7
// (2 x float4, fully coalesced). Tournament result is assignment-independent.
// ---------------------------------------------------------------------------
__global__ __launch_bounds__(256)
void k_select(const float* __restrict__ dist, int* __restrict__ nidx)
{
    const int wv = threadIdx.x >> 6, lane = threadIdx.x & 63;
    const int p = blockIdx.x * 4 + wv;             // global point 0..32767
    const float* row = dist + (size_t)p * NP;

    float d[8];
    {
        const float4 va = *(const float4*)(row + lane * 8);
        const float4 vb = *(const float4*)(row + lane * 8 + 4);
        d[0] = va.x; d[1] = va.y; d[2] = va.z; d[3] = va.w;
        d[4] = vb.x; d[5] = vb.y; d[6] = vb.z; d[7] = vb.w;
    }

    for (int r = 0; r < KNN; ++r) {
        float bd = d[0]; int bi = 0;
        #pragma unroll
        for (int i = 1; i < 8; ++i)
            if (d[i] < bd) { bd = d[i]; bi = i; }   // strict < keeps lowest i on tie
        int bq = lane * 8 + bi;
        #pragma unroll
        for (int s = 32; s > 0; s >>= 1) {
            const float od = __shfl_down(bd, s, 64);
            const int oq = __shfl_down(bq, s, 64);
            if (od < bd || (od == bd && oq < bq)) { bd = od; bq = oq; }
        }
        const int win = __shfl(bq, 0, 64);
        if (lane == 0) nidx[(size_t)p * KNN + r] = ((p >> 9) << 9) | win;
        if ((win >> 3) == lane) {
            const int wi = win & 7;
            #pragma unroll
            for (int i = 0; i < 8; ++i) if (wi == i) d[i] = 3.4e38f;
        }
    }
}

// ---------------------------------------------------------------------------
// Kernel 4: u = x@Wd+gb1, v = x@Wb via 2-pass split MFMA (A hi+lo, B hi only).
// 32 points/block, full problem (2048 blocks; bid>>10 picks u vs v).
// ---------------------------------------------------------------------------
__global__ __launch_bounds__(256)
void k_uv(const ushort* __restrict__ ehi, const ushort* __restrict__ elo,
          const ushort* __restrict__ Wdh, const ushort* __restrict__ Wbh,
          const float* __restrict__ gb1,
          float* __restrict__ u, float* __restrict__ v)
{
    const int t = threadIdx.x, w = t >> 6, lane = t & 63;
    const int l15 = lane & 15, quad = lane >> 4;
    const int isV = blockIdx.x >> 10;
    const int m0 = (blockIdx.x & 1023) * 32;
    const ushort* Wh = isV ? Wbh : Wdh;
    float* out = isV ? v : u;
    const int mt = w & 1, ch = w >> 1;

    const size_t arow = (size_t)(m0 + mt * 16 + l15) * 256 + quad * 8;

    f32x4 acc[8];
    #pragma unroll
    for (int nt = 0; nt < 8; ++nt) acc[nt] = (f32x4){0.f, 0.f, 0.f, 0.f};

    #pragma unroll
    for (int s = 0; s < 8; ++s) {
        const s16x8 ah = *(const s16x8*)(ehi + arow + s * 32);
        const s16x8 al = *(const s16x8*)(elo + arow + s * 32);
        #pragma unroll
        for (int nt = 0; nt < 8; ++nt) {
            const int n = (ch * 8 + nt) * 16 + l15;
            const size_t bo = (size_t)n * 256 + s * 32 + quad * 8;
            const s16x8 bh = *(const s16x8*)(Wh + bo);
            acc[nt] = __builtin_amdgcn_mfma_f32_16x16x32_bf16(ah, bh, acc[nt], 0, 0, 0);
            acc[nt] = __builtin_amdgcn_mfma_f32_16x16x32_bf16(al, bh, acc[nt], 0, 0, 0);
        }
    }

    #pragma unroll
    for (int nt = 0; nt < 8; ++nt) {
        const int col = (ch * 8 + nt) * 16 + l15;
        const float bias = isV ? 0.f : gb1[col];
        #pragma unroll
        for (int r = 0; r < 4; ++r) {
            const int row = mt * 16 + quad * 4 + r;
            out[(size_t)(m0 + row) * 256 + col] = acc[nt][r] + bias;
        }
    }
}

// ---------------------------------------------------------------------------
// Kernel 5: edge GEMM + max aggregation. Block = 8 points (64 edges), 4 waves;
// wave w = all 64 edges x cols w*64..+63. 2-pass split (A hi+lo, B hi only).
// Software-pipelined A-staging (LOADR a full k-step ahead of SPLITW).
// Full problem: 4096 blocks, XCD swizzle (8 cells per XCD).
// ---------------------------------------------------------------------------
__global__ __launch_bounds__(256)
void k_edge(const float* __restrict__ u, const float* __restrict__ v,
            const int* __restrict__ nidx,
            const ushort* __restrict__ g2h,
            const float* __restrict__ hb,
            float* __restrict__ part)
{
    __shared__ ushort Abuf[2][2][2304];   // [dbuf][hi/lo][edge*36+k], 18.4 KB

    const int t = threadIdx.x, w = t >> 6, lane = t & 63;
    const int l15 = lane & 15, quad = lane >> 4;

    const int b = blockIdx.x;
    const int xcd = b & 7, rest = b >> 3;        // rest 0..511
    const int cell = xcd * 8 + (rest >> 6);      // 0..63
    const int pl0 = cell * NP + (rest & 63) * 8;

    const int se = t >> 2, kq = t & 3;
    const int surow = pl0 + (se >> 3);
    int svrow = nidx[(size_t)surow * KNN + (se & 7)];
    if ((unsigned)svrow >= (unsigned)NTOT) svrow = 0;

    float4 ua, ub, va, vb;

    #define LOADR(S)                                                             \
    {                                                                            \
        const int k0 = (S) * 32 + kq * 8;                                        \
        ua = *(const float4*)(u + (size_t)surow * 256 + k0);                     \
        ub = *(const float4*)(u + (size_t)surow * 256 + k0 + 4);                 \
        va = *(const float4*)(v + (size_t)svrow * 256 + k0);                     \
        vb = *(const float4*)(v + (size_t)svrow * 256 + k0 + 4);                 \
    }
    #define SPLITW(BUF)                                                          \
    {                                                                            \
        const float sv[8] = {                                                    \
            fmaxf(ua.x + va.x, 0.f), fmaxf(ua.y + va.y, 0.f),                    \
            fmaxf(ua.z + va.z, 0.f), fmaxf(ua.w + va.w, 0.f),                    \
            fmaxf(ub.x + vb.x, 0.f), fmaxf(ub.y + vb.y, 0.f),                    \
            fmaxf(ub.z + vb.z, 0.f), fmaxf(ub.w + vb.w, 0.f)};                   \
        union { uint2 q[2]; ushort us[8]; } th, tl;                              \
        _Pragma("unroll")                                                        \
        for (int j = 0; j < 8; ++j) { split2(sv[j], th.us[j], tl.us[j]); }       \
        *(uint2*)&Abuf[BUF][0][se * 36 + kq * 8]     = th.q[0];                  \
        *(uint2*)&Abuf[BUF][0][se * 36 + kq * 8 + 4] = th.q[1];                  \
        *(uint2*)&Abuf[BUF][1][se * 36 + kq * 8]     = tl.q[0];                  \
        *(uint2*)&Abuf[BUF][1][se * 36 + kq * 8 + 4] = tl.q[1];                  \
    }

    f32x4 acc[4][4];
    #pragma unroll
    for (int mt = 0; mt < 4; ++mt)
        #pragma unroll
        for (int nt = 0; nt < 4; ++nt) acc[mt][nt] = (f32x4){0.f, 0.f, 0.f, 0.f};

    LOADR(0);
    SPLITW(0);
    LOADR(1);
    for (int s = 0; s < 8; ++s) {
        __syncthreads();
        if (s < 7) {
            SPLITW((s + 1) & 1);
            if (s < 6) LOADR(s + 2);
        }

        const int k0 = s * 32 + quad * 8;
        s16x8 ah[4], al[4];
        #pragma unroll
        for (int mt = 0; mt < 4; ++mt) {
            const int ao = (mt * 16 + l15) * 36 + quad * 8;
            union { uint2 q[2]; s16x8 v8; } Th, Tl;
            Th.q[0] = *(const uint2*)&Abuf[s & 1][0][ao];
            Th.q[1] = *(const uint2*)&Abuf[s & 1][0][ao + 4];
            Tl.q[0] = *(const uint2*)&Abuf[s & 1][1][ao];
            Tl.q[1] = *(const uint2*)&Abuf[s & 1][1][ao + 4];
            ah[mt] = Th.v8; al[mt] = Tl.v8;
        }
        #pragma unroll
        for (int nt = 0; nt < 4; ++nt) {
            const int n = w * 64 + nt * 16 + l15;
            const s16x8 bh = *(const s16x8*)(g2h + (size_t)n * 256 + k0);
            #pragma unroll
            for (int mt = 0; mt < 4; ++mt) {
                acc[mt][nt] = __builtin_amdgcn_mfma_f32_16x16x32_bf16(ah[mt], bh, acc[mt][nt], 0, 0, 0);
                acc[mt][nt] = __builtin_amdgcn_mfma_f32_16x16x32_bf16(al[mt], bh, acc[mt][nt], 0, 0, 0);
            }
        }
    }
    #undef LOADR
    #undef SPLITW

    const int slot = rest & 63;
    #pragma unroll
    for (int nt = 0; nt < 4; ++nt) {
        float rm = -3.4e38f;
        #pragma unroll
        for (int mt = 0; mt < 4; ++mt)
            rm = fmaxf(rm, fmaxf(fmaxf(acc[mt][nt][0], acc[mt][nt][1]),
                                 fmaxf(acc[mt][nt][2], acc[mt][nt][3])));
        rm = fmaxf(rm, __shfl_xor(rm, 16, 64));
        rm = fmaxf(rm, __shfl_xor(rm, 32, 64));
        if (quad == 0) {
            const int col = w * 64 + nt * 16 + l15;
            part[((size_t)cell * 64 + slot) * 256 + col] = rm + hb[col];
        }
    }
}

// ---------------------------------------------------------------------------
// Kernel 6: reduce 64 partial maxes per cell, final MLP (f32), L2 normalize.
// ---------------------------------------------------------------------------
__global__ __launch_bounds__(256)
void k_final(const float* __restrict__ part,
             const float* __restrict__ lW1, const float* __restrict__ lb1,
             const float* __restrict__ lW2, const float* __restrict__ lb2,
             float* __restrict__ out)
{
    __shared__ float pooled[256];
    __shared__ float hid[256];
    __shared__ float red[4];

    const int b = blockIdx.x;
    const int t = threadIdx.x;

    float m = -3.4e38f;
    for (int s = 0; s < 64; ++s)
        m = fmaxf(m, part[((size_t)b * 64 + s) * 256 + t]);
    pooled[t] = m;
    __syncthreads();

    float h = lb1[t];
    for (int k = 0; k < 256; k += 4) {
        #pragma unroll
        for (int kk = 0; kk < 4; ++kk)
            h += pooled[k + kk] * lW1[(k + kk) * 256 + t];
    }
    hid[t] = fmaxf(h, 0.f);
    __syncthreads();

    float o = lb2[t];
    for (int k = 0; k < 256; k += 4) {
        #pragma unroll
        for (int kk = 0; kk < 4; ++kk)
            o += hid[k + kk] * lW2[(k + kk) * 256 + t];
    }

    float ss = o * o;
    #pragma unroll
    for (int s = 32; s > 0; s >>= 1) ss += __shfl_down(ss, s, 64);
    if ((t & 63) == 0) red[t >> 6] = ss;
    __syncthreads();
    const float tot = red[0] + red[1] + red[2] + red[3];
    const float rn = 1.f / fmaxf(sqrtf(tot), 1e-12f);
    out[b * 256 + t] = o * rn;
}

// ---------------------------------------------------------------------------
extern "C" void kernel_launch(void* const* d_in, const int* in_sizes, int n_in,
                              void* d_out, int out_size, void* d_ws, size_t ws_size,
                              hipStream_t stream)
{
    (void)n_in; (void)out_size; (void)ws_size;

    const float* class_table = (const float*)d_in[0];
    const float* cW1 = (const float*)d_in[1];
    const float* cb1 = (const float*)d_in[2];
    const float* cW2 = (const float*)d_in[3];
    const float* cb2 = (const float*)d_in[4];
    const float* pW1 = (const float*)d_in[5];
    const float* pb1 = (const float*)d_in[6];
    const float* pW2 = (const float*)d_in[7];
    const float* pb2 = (const float*)d_in[8];
    const float* mW  = (const float*)d_in[9];
    const float* mb  = (const float*)d_in[10];
    const float* gW1 = (const float*)d_in[11];
    const float* gb1 = (const float*)d_in[12];
    const float* g_gamma = (const float*)d_in[13];
    const float* g_beta  = (const float*)d_in[14];
    const float* gW2 = (const float*)d_in[15];
    const float* gb2 = (const float*)d_in[16];
    const float* lW1 = (const float*)d_in[17];
    const float* lb1 = (const float*)d_in[18];
    const float* lW2 = (const float*)d_in[19];
    const float* lb2 = (const float*)d_in[20];
    const float* positions = (const float*)d_in[21];
    const float* colors    = (const float*)d_in[22];
    const int*  cls        = (const int*)d_in[23];

    const int cstride = (in_sizes[23] == 2 * NTOT) ? 2 : 1;

    // workspace layout (bytes), total ~174 MB (ws_size ~268 MB per the
    // harness fill counters: WRITE_SIZE = 2.685e8 B per d_ws poison).
    char* base = (char*)d_ws;
    float*   part   = (float*)(base + 0);               //   4,194,304
    ushort*  Wdh    = (ushort*)(base + 4194304);
    ushort*  Wdl    = (ushort*)(base + 4325376);
    ushort*  Wbh    = (ushort*)(base + 4456448);
    ushort*  Wbl    = (ushort*)(base + 4587520);
    ushort*  g2h    = (ushort*)(base + 4718592);
    ushort*  g2l    = (ushort*)(base + 4849664);
    float*   hb     = (float*)(base + 4980736);
    ushort*  cW2Th  = (ushort*)(base + 4981760);
    ushort*  cW2Tl  = (ushort*)(base + 5014528);
    ushort*  pW2Th  = (ushort*)(base + 5047296);
    ushort*  pW2Tl  = (ushort*)(base + 5080064);
    ushort*  WcTh   = (ushort*)(base + 5112832);
    ushort*  WcTl   = (ushort*)(base + 5145600);
    ushort*  WpTh   = (ushort*)(base + 5178368);
    ushort*  WpTl   = (ushort*)(base + 5211136);
    float*   classMn= (float*)(base + 5243904);         //      31,744
    float*   cbM    = (float*)(base + 5275648);
    float*   pbM    = (float*)(base + 5276672);
    int*     nidx   = (int*)(base + 5277696);           //   1,048,576
    float*   sqn    = (float*)(base + 6326272);         //     131,072
    ushort*  ehi    = (ushort*)(base + 6457344);        //  16,777,216
    ushort*  elo    = (ushort*)(base + 23234560);       //  16,777,216
    float*   dist   = (float*)(base + 40011776);        //  67,108,864
    float*   v      = (float*)(base + 107120640);       //  33,554,432
    float*   u      = (float*)(base + 140675072);       //  33,554,432
    float* out = (float*)d_out;

    k_cvt<<<897, 256, 0, stream>>>(gW1, gW2, g_gamma, g_beta, gb2, cW2, pW2,
                                   Wdh, Wdl, Wbh, Wbl, g2h, g2l, hb,
                                   cW2Th, cW2Tl, pW2Th, pW2Tl);
    k_fold<<<130, 256, 0, stream>>>(cW2, pW2, cb2, pb2, mW,
                                    WcTh, WcTl, WpTh, WpTl, cbM, pbM);
    k_cls<<<31, 256, 0, stream>>>(class_table, mW, classMn);

    k_embed<<<NTOT / 16, 256, 0, stream>>>(classMn, cW1, cb1, cb2, pW1, pb1, pb2,
                                           mb, cW2Th, cW2Tl, pW2Th, pW2Tl,
                                           WcTh, WcTl, WpTh, WpTl, cbM, pbM,
                                           positions, colors, cls, cstride,
                                           ehi, elo, sqn);
    k_gram<<<NB * 32, 256, 0, stream>>>(ehi, elo, sqn, dist);
    k_select<<<NTOT / 4, 256, 0, stream>>>(dist, nidx);
    k_uv<<<2 * NTOT / 32, 256, 0, stream>>>(ehi, elo, Wdh, Wbh, gb1, u, v);
    k_edge<<<NTOT / 8, 256, 0, stream>>>(u, v, nidx, g2h, hb, part);
    k_final<<<NB, 256, 0, stream>>>(part, lW1, lb1, lW2, lb2, out);
}

// Round 15
// 533.152 us; speedup vs baseline: 1.3289x; 1.0263x over previous
//
#include <hip/hip_runtime.h>

#define EDIM 256
#define KNN 8
#define NB 64
#define NP 512
#define NTOT (NB * NP)

typedef short s16x8 __attribute__((ext_vector_type(8)));
typedef float f32x4 __attribute__((ext_vector_type(4)));
typedef unsigned short ushort;

__device__ __forceinline__ ushort f2b(float f) {
    unsigned u = __float_as_uint(f);
    u = (u + 0x7fffu + ((u >> 16) & 1u)) >> 16;   // RNE
    return (ushort)u;
}
__device__ __forceinline__ float b2f(ushort h) {
    return __uint_as_float(((unsigned)h) << 16);
}
__device__ __forceinline__ void split2(float x, ushort& h, ushort& l) {
    h = f2b(x);
    l = f2b(x - b2f(h));
}
// truncation split (edge hot path): pair error ~2^-16 relative, 2x fewer VALU
__device__ __forceinline__ ushort f2bt(float f) {
    return (ushort)(__float_as_uint(f) >> 16);
}
__device__ __forceinline__ void split2t(float x, ushort& h, ushort& l) {
    h = f2bt(x);
    l = f2bt(x - b2f(h));
}

// ---------------------------------------------------------------------------
// Kernel 0a: weight prep -> transposed bf16 hi/lo pairs.
// ---------------------------------------------------------------------------
__global__ __launch_bounds__(256)
void k_cvt(const float* __restrict__ gW1, const float* __restrict__ gW2,
           const float* __restrict__ g_gamma, const float* __restrict__ g_beta,
           const float* __restrict__ gb2,
           const float* __restrict__ cW2, const float* __restrict__ pW2,
           ushort* __restrict__ Wdh, ushort* __restrict__ Wdl,
           ushort* __restrict__ Wbh, ushort* __restrict__ Wbl,
           ushort* __restrict__ g2h, ushort* __restrict__ g2l,
           float* __restrict__ hb,
           ushort* __restrict__ cW2Th, ushort* __restrict__ cW2Tl,
           ushort* __restrict__ pW2Th, ushort* __restrict__ pW2Tl)
{
    const int gid = blockIdx.x * 256 + threadIdx.x;
    ushort h, l;
    if (gid < 65536) {
        const int n = gid >> 8, k = gid & 255;
        split2(gW1[k * 256 + n] - gW1[(k + 256) * 256 + n], h, l);
        Wdh[gid] = h; Wdl[gid] = l;
    } else if (gid < 131072) {
        const int i = gid - 65536, n = i >> 8, k = i & 255;
        split2(gW1[(k + 256) * 256 + n], h, l);
        Wbh[i] = h; Wbl[i] = l;
    } else if (gid < 196608) {
        const int i = gid - 131072, n = i >> 8, k = i & 255;
        split2(g_gamma[k] * gW2[k * 256 + n], h, l);
        g2h[i] = h; g2l[i] = l;
    } else if (gid < 196864) {
        const int n = gid - 196608;
        float s = gb2[n];
        for (int k = 0; k < 256; ++k) s += g_beta[k] * gW2[k * 256 + n];
        hb[n] = s;
    } else if (gid < 213248) {
        const int i = gid - 196864, n = i >> 6, k = i & 63;
        split2(cW2[k * 256 + n], h, l);
        cW2Th[i] = h; cW2Tl[i] = l;
    } else if (gid < 229632) {
        const int i = gid - 213248, n = i >> 6, k = i & 63;
        split2(pW2[k * 256 + n], h, l);
        pW2Th[i] = h; pW2Tl[i] = l;
    }
}

// ---------------------------------------------------------------------------
// Kernel 0b: fold merge GEMM into the MLP weights (linearity).
// ---------------------------------------------------------------------------
__global__ __launch_bounds__(256)
void k_fold(const float* __restrict__ cW2, const float* __restrict__ pW2,
            const float* __restrict__ cb2, const float* __restrict__ pb2,
            const float* __restrict__ mW,
            ushort* __restrict__ WcTh, ushort* __restrict__ WcTl,
            ushort* __restrict__ WpTh, ushort* __restrict__ WpTl,
            float* __restrict__ cbM, float* __restrict__ pbM)
{
    const int gid = blockIdx.x * 256 + threadIdx.x;
    ushort h, l;
    if (gid < 16384) {
        const int j = gid >> 8, n = gid & 255;
        float s = 0.f;
        for (int k = 0; k < 256; ++k) s += cW2[j * 256 + k] * mW[(256 + k) * 256 + n];
        split2(s, h, l);
        WcTh[n * 64 + j] = h; WcTl[n * 64 + j] = l;
    } else if (gid < 32768) {
        const int i = gid - 16384, j = i >> 8, n = i & 255;
        float s = 0.f;
        for (int k = 0; k < 256; ++k) s += pW2[j * 256 + k] * mW[(512 + k) * 256 + n];
        split2(s, h, l);
        WpTh[n * 64 + j] = h; WpTl[n * 64 + j] = l;
    } else if (gid < 33024) {
        const int n = gid - 32768;
        float s = 0.f;
        for (int k = 0; k < 256; ++k) s += cb2[k] * mW[(256 + k) * 256 + n];
        cbM[n] = s;
    } else if (gid < 33280) {
        const int n = gid - 33024;
        float s = 0.f;
        for (int k = 0; k < 256; ++k) s += pb2[k] * mW[(512 + k) * 256 + n];
        pbM[n] = s;
    }
}

// ---------------------------------------------------------------------------
// Kernel 0c: classMn[c] = (class_table[c] / ||class_table[c]||) @ M0.
// ---------------------------------------------------------------------------
__global__ __launch_bounds__(256)
void k_cls(const float* __restrict__ ct, const float* __restrict__ mW,
           float* __restrict__ classMn)
{
    __shared__ float ctn[256];
    __shared__ float red[4];
    const int c = blockIdx.x, t = threadIdx.x;
    const float v = ct[c * 256 + t];
    float ss = v * v;
    #pragma unroll
    for (int s = 32; s > 0; s >>= 1) ss += __shfl_down(ss, s, 64);
    if ((t & 63) == 0) red[t >> 6] = ss;
    __syncthreads();
    const float tot = red[0] + red[1] + red[2] + red[3];
    const float r = 1.f / fmaxf(sqrtf(tot), 1e-12f);
    ctn[t] = v * r;
    __syncthreads();
    float s = 0.f;
    for (int k = 0; k < 256; ++k) s += ctn[k] * mW[k * 256 + t];
    classMn[c * 256 + t] = s;
}

// ---------------------------------------------------------------------------
// Kernel 1: embeddings via folded GEMMs. 16 obj/block, full problem (2048).
// ---------------------------------------------------------------------------
__global__ __launch_bounds__(256)
void k_embed(const float* __restrict__ classMn,
             const float* __restrict__ cW1, const float* __restrict__ cb1,
             const float* __restrict__ cb2,
             const float* __restrict__ pW1, const float* __restrict__ pb1,
             const float* __restrict__ pb2,
             const float* __restrict__ mb,
             const ushort* __restrict__ cW2Th, const ushort* __restrict__ cW2Tl,
             const ushort* __restrict__ pW2Th, const ushort* __restrict__ pW2Tl,
             const ushort* __restrict__ WcTh, const ushort* __restrict__ WcTl,
             const ushort* __restrict__ WpTh, const ushort* __restrict__ WpTl,
             const float* __restrict__ cbM, const float* __restrict__ pbM,
             const float* __restrict__ positions, const float* __restrict__ colors,
             const int* __restrict__ cls, const int cstride,
             ushort* __restrict__ ehi, ushort* __restrict__ elo,
             float* __restrict__ sqn)
{
    __shared__ __align__(16) ushort Ahc[16 * 72];
    __shared__ __align__(16) ushort Alc[16 * 72];
    __shared__ __align__(16) ushort Ahp[16 * 72];
    __shared__ __align__(16) ushort Alp[16 * 72];
    __shared__ float sqc[16][4], sqp_[16][4], sqe[16][4];

    const int t = threadIdx.x, w = t >> 6, lane = t & 63;
    const int l15 = lane & 15, quad = lane >> 4;
    const int obase = blockIdx.x * 16;

    {
        const int o = lane >> 4;
        const int objl = w * 4 + o;
        const int gobj = obase + objl;
        const float c0 = colors[gobj * 3], c1 = colors[gobj * 3 + 1], c2 = colors[gobj * 3 + 2];
        const float q0 = positions[gobj * 3], q1 = positions[gobj * 3 + 1], q2 = positions[gobj * 3 + 2];
        const int u0 = (lane & 15) * 4;
        #pragma unroll
        for (int uu = 0; uu < 4; ++uu) {
            const int u = u0 + uu;
            const float hc = fmaxf(cb1[u] + c0 * cW1[u] + c1 * cW1[64 + u] + c2 * cW1[128 + u], 0.f);
            const float hp = fmaxf(pb1[u] + q0 * pW1[u] + q1 * pW1[64 + u] + q2 * pW1[128 + u], 0.f);
            ushort h, l;
            split2(hc, h, l); Ahc[objl * 72 + u] = h; Alc[objl * 72 + u] = l;
            split2(hp, h, l); Ahp[objl * 72 + u] = h; Alp[objl * 72 + u] = l;
        }
    }
    __syncthreads();

    f32x4 aco[4], ape[4];
    #pragma unroll
    for (int nt = 0; nt < 4; ++nt) { aco[nt] = (f32x4){0.f,0.f,0.f,0.f}; ape[nt] = (f32x4){0.f,0.f,0.f,0.f}; }

    #pragma unroll
    for (int kt = 0; kt < 2; ++kt) {
        const int ao = l15 * 72 + kt * 32 + quad * 8;
        const s16x8 ahc = *(const s16x8*)&Ahc[ao];
        const s16x8 alc = *(const s16x8*)&Alc[ao];
        const s16x8 ahp = *(const s16x8*)&Ahp[ao];
        const s16x8 alp = *(const s16x8*)&Alp[ao];
        #pragma unroll
        for (int nt = 0; nt < 4; ++nt) {
            const int n = w * 64 + nt * 16 + l15;
            const size_t bo = (size_t)n * 64 + kt * 32 + quad * 8;
            const s16x8 cbh = *(const s16x8*)(cW2Th + bo);
            const s16x8 cbl = *(const s16x8*)(cW2Tl + bo);
            const s16x8 pbh = *(const s16x8*)(pW2Th + bo);
            const s16x8 pbl = *(const s16x8*)(pW2Tl + bo);
            aco[nt] = __builtin_amdgcn_mfma_f32_16x16x32_bf16(ahc, cbh, aco[nt], 0, 0, 0);
            ape[nt] = __builtin_amdgcn_mfma_f32_16x16x32_bf16(ahp, pbh, ape[nt], 0, 0, 0);
            aco[nt] = __builtin_amdgcn_mfma_f32_16x16x32_bf16(alc, cbh, aco[nt], 0, 0, 0);
            ape[nt] = __builtin_amdgcn_mfma_f32_16x16x32_bf16(alp, pbh, ape[nt], 0, 0, 0);
            aco[nt] = __builtin_amdgcn_mfma_f32_16x16x32_bf16(ahc, cbl, aco[nt], 0, 0, 0);
            ape[nt] = __builtin_amdgcn_mfma_f32_16x16x32_bf16(ahp, pbl, ape[nt], 0, 0, 0);
        }
    }

    float sc[4] = {0.f,0.f,0.f,0.f}, sp[4] = {0.f,0.f,0.f,0.f};
    #pragma unroll
    for (int nt = 0; nt < 4; ++nt) {
        const int col = w * 64 + nt * 16 + l15;
        const float cbv = cb2[col], pbv = pb2[col];
        #pragma unroll
        for (int r = 0; r < 4; ++r) {
            const float co = aco[nt][r] + cbv;
            const float pe = ape[nt][r] + pbv;
            sc[r] += co * co;
            sp[r] += pe * pe;
        }
    }
    #pragma unroll
    for (int s = 8; s > 0; s >>= 1) {
        #pragma unroll
        for (int r = 0; r < 4; ++r) {
            sc[r] += __shfl_xor(sc[r], s, 64);
            sp[r] += __shfl_xor(sp[r], s, 64);
        }
    }
    if (l15 == 0) {
        #pragma unroll
        for (int r = 0; r < 4; ++r) { sqc[quad * 4 + r][w] = sc[r]; sqp_[quad * 4 + r][w] = sp[r]; }
    }
    __syncthreads();

    float rco[4], rpe[4];
    #pragma unroll
    for (int r = 0; r < 4; ++r) {
        const int row = quad * 4 + r;
        rco[r] = 1.f / fmaxf(sqrtf(sqc[row][0] + sqc[row][1] + sqc[row][2] + sqc[row][3]), 1e-12f);
        rpe[r] = 1.f / fmaxf(sqrtf(sqp_[row][0] + sqp_[row][1] + sqp_[row][2] + sqp_[row][3]), 1e-12f);
    }

    f32x4 ac[4], ap[4];
    #pragma unroll
    for (int nt = 0; nt < 4; ++nt) { ac[nt] = (f32x4){0.f,0.f,0.f,0.f}; ap[nt] = (f32x4){0.f,0.f,0.f,0.f}; }

    #pragma unroll
    for (int kt = 0; kt < 2; ++kt) {
        const int ao = l15 * 72 + kt * 32 + quad * 8;
        const s16x8 ahc = *(const s16x8*)&Ahc[ao];
        const s16x8 alc = *(const s16x8*)&Alc[ao];
        const s16x8 ahp = *(const s16x8*)&Ahp[ao];
        const s16x8 alp = *(const s16x8*)&Alp[ao];
        #pragma unroll
        for (int nt = 0; nt < 4; ++nt) {
            const int n = w * 64 + nt * 16 + l15;
            const size_t bo = (size_t)n * 64 + kt * 32 + quad * 8;
            const s16x8 cbh = *(const s16x8*)(WcTh + bo);
            const s16x8 cbl = *(const s16x8*)(WcTl + bo);
            const s16x8 pbh = *(const s16x8*)(WpTh + bo);
            const s16x8 pbl = *(const s16x8*)(WpTl + bo);
            ac[nt] = __builtin_amdgcn_mfma_f32_16x16x32_bf16(ahc, cbh, ac[nt], 0, 0, 0);
            ap[nt] = __builtin_amdgcn_mfma_f32_16x16x32_bf16(ahp, pbh, ap[nt], 0, 0, 0);
            ac[nt] = __builtin_amdgcn_mfma_f32_16x16x32_bf16(alc, cbh, ac[nt], 0, 0, 0);
            ap[nt] = __builtin_amdgcn_mfma_f32_16x16x32_bf16(alp, pbh, ap[nt], 0, 0, 0);
            ac[nt] = __builtin_amdgcn_mfma_f32_16x16x32_bf16(ahc, cbl, ac[nt], 0, 0, 0);
            ap[nt] = __builtin_amdgcn_mfma_f32_16x16x32_bf16(ahp, pbl, ap[nt], 0, 0, 0);
        }
    }

    int ci[4];
    #pragma unroll
    for (int r = 0; r < 4; ++r) {
        const int gobj = obase + quad * 4 + r;
        int c = cls[(size_t)gobj * cstride];
        if ((unsigned)c > 30u) c = 0;
        ci[r] = c;
    }

    float rp[4] = {0.f,0.f,0.f,0.f};
    #pragma unroll
    for (int nt = 0; nt < 4; ++nt) {
        const int col = w * 64 + nt * 16 + l15;
        const float mbv = mb[col], cbMv = cbM[col], pbMv = pbM[col];
        #pragma unroll
        for (int r = 0; r < 4; ++r) {
            const int row = quad * 4 + r;
            const float e = classMn[ci[r] * 256 + col]
                          + rco[r] * (ac[nt][r] + cbMv)
                          + rpe[r] * (ap[nt][r] + pbMv) + mbv;
            ushort h, l;
            split2(e, h, l);
            ehi[(size_t)(obase + row) * 256 + col] = h;
            elo[(size_t)(obase + row) * 256 + col] = l;
            rp[r] += e * e;
        }
    }
    #pragma unroll
    for (int s = 8; s > 0; s >>= 1) {
        #pragma unroll
        for (int r = 0; r < 4; ++r) rp[r] += __shfl_xor(rp[r], s, 64);
    }
    if (l15 == 0) {
        #pragma unroll
        for (int r = 0; r < 4; ++r) sqe[quad * 4 + r][w] = rp[r];
    }
    __syncthreads();
    if (t < 16) sqn[obase + t] = sqe[t][0] + sqe[t][1] + sqe[t][2] + sqe[t][3];
}

// ---------------------------------------------------------------------------
// Kernel 2: Gram/distance via 3-pass split MFMA, 128x64 tile per block.
// XCD swizzle: cell c's 32 blocks land on XCD c>>3 (dist stays L2-local
// for the matching select blocks).
// ---------------------------------------------------------------------------
__global__ __launch_bounds__(256)
void k_gram(const ushort* __restrict__ ehi, const ushort* __restrict__ elo,
            const float* __restrict__ sqn, float* __restrict__ dist)
{
    const int t = threadIdx.x, w = t >> 6, lane = t & 63;
    const int l15 = lane & 15, quad = lane >> 4;
    const int xcd = blockIdx.x & 7, rest = blockIdx.x >> 3;   // rest 0..255
    const int b_local = xcd * 8 + (rest >> 5);                // 0..63
    const int tile = rest & 31;
    const int p0 = (tile >> 3) * 128, q0 = (tile & 7) * 64;
    const size_t cb = (size_t)b_local * NP;

    f32x4 acc[2][4];
    #pragma unroll
    for (int sub = 0; sub < 2; ++sub)
        #pragma unroll
        for (int nt = 0; nt < 4; ++nt) acc[sub][nt] = (f32x4){0.f, 0.f, 0.f, 0.f};

    #pragma unroll
    for (int s = 0; s < 8; ++s) {
        s16x8 ah[2], al[2];
        #pragma unroll
        for (int sub = 0; sub < 2; ++sub) {
            const size_t ao = (cb + p0 + sub * 64 + 16 * w + l15) * 256 + s * 32 + quad * 8;
            ah[sub] = *(const s16x8*)(ehi + ao);
            al[sub] = *(const s16x8*)(elo + ao);
        }
        #pragma unroll
        for (int nt = 0; nt < 4; ++nt) {
            const size_t bo = (cb + q0 + nt * 16 + l15) * 256 + s * 32 + quad * 8;
            const s16x8 bh = *(const s16x8*)(ehi + bo);
            const s16x8 bl = *(const s16x8*)(elo + bo);
            #pragma unroll
            for (int sub = 0; sub < 2; ++sub) {
                acc[sub][nt] = __builtin_amdgcn_mfma_f32_16x16x32_bf16(ah[sub], bh, acc[sub][nt], 0, 0, 0);
                acc[sub][nt] = __builtin_amdgcn_mfma_f32_16x16x32_bf16(al[sub], bh, acc[sub][nt], 0, 0, 0);
                acc[sub][nt] = __builtin_amdgcn_mfma_f32_16x16x32_bf16(ah[sub], bl, acc[sub][nt], 0, 0, 0);
            }
        }
    }

    #pragma unroll
    for (int sub = 0; sub < 2; ++sub) {
        float sqp[4];
        #pragma unroll
        for (int r = 0; r < 4; ++r)
            sqp[r] = sqn[cb + p0 + sub * 64 + 16 * w + quad * 4 + r];
        #pragma unroll
        for (int nt = 0; nt < 4; ++nt) {
            const int colq = q0 + nt * 16 + l15;
            const float sq_q = sqn[cb + colq];
            #pragma unroll
            for (int r = 0; r < 4; ++r) {
                const int rowp = p0 + sub * 64 + 16 * w + quad * 4 + r;
                dist[(cb + rowp) * NP + colq] = (sqp[r] + sq_q) - 2.f * acc[sub][nt][r];
            }
        }
    }
}

// ---------------------------------------------------------------------------
// Kernel 3: top-8 smallest per point (ties -> lowest index). One wave/point.
// XCD swizzle matches k_gram (cell c -> XCD c>>3) for L2-local dist reads.
// ---------------------------------------------------------------------------
__global__ __launch_bounds__(256)
void k_select(const float* __restrict__ dist, int* __restrict__ nidx)
{
    const int wv = threadIdx.x >> 6, lane = threadIdx.x & 63;
    const int xcd = blockIdx.x & 7, rest = blockIdx.x >> 3;   // rest 0..1023
    const int cell = xcd * 8 + (rest >> 7);                   // 0..63
    const int p = cell * NP + (rest & 127) * 4 + wv;          // global point
    const float* row = dist + (size_t)p * NP;

    float d[8];
    {
        const float4 va = *(const float4*)(row + lane * 8);
        const float4 vb = *(const float4*)(row + lane * 8 + 4);
        d[0] = va.x; d[1] = va.y; d[2] = va.z; d[3] = va.w;
        d[4] = vb.x; d[5] = vb.y; d[6] = vb.z; d[7] = vb.w;
    }

    for (int r = 0; r < KNN; ++r) {
        float bd = d[0]; int bi = 0;
        #pragma unroll
        for (int i = 1; i < 8; ++i)
            if (d[i] < bd) { bd = d[i]; bi = i; }   // strict < keeps lowest i on tie
        int bq = lane * 8 + bi;
        #pragma unroll
        for (int s = 32; s > 0; s >>= 1) {
            const float od = __shfl_down(bd, s, 64);
            const int oq = __shfl_down(bq, s, 64);
            if (od < bd || (od == bd && oq < bq)) { bd = od; bq = oq; }
        }
        const int win = __shfl(bq, 0, 64);
        if (lane == 0) nidx[(size_t)p * KNN + r] = ((p >> 9) << 9) | win;
        if ((win >> 3) == lane) {
            const int wi = win & 7;
            #pragma unroll
            for (int i = 0; i < 8; ++i) if (wi == i) d[i] = 3.4e38f;
        }
    }
}

// ---------------------------------------------------------------------------
// Kernel 4: u = x@Wd+gb1, v = x@Wb via 2-pass split MFMA (A hi+lo, B hi only).
// 64 points/block (halves B L2 traffic): wave = 2 m-frags x 128 cols.
// MFMA order per output element unchanged -> bit-identical results.
// ---------------------------------------------------------------------------
__global__ __launch_bounds__(256)
void k_uv(const ushort* __restrict__ ehi, const ushort* __restrict__ elo,
          const ushort* __restrict__ Wdh, const ushort* __restrict__ Wbh,
          const float* __restrict__ gb1,
          float* __restrict__ u, float* __restrict__ v)
{
    const int t = threadIdx.x, w = t >> 6, lane = t & 63;
    const int l15 = lane & 15, quad = lane >> 4;
    const int isV = blockIdx.x >> 9;           // 1024 blocks total
    const int m0 = (blockIdx.x & 511) * 64;
    const ushort* Wh = isV ? Wbh : Wdh;
    float* out = isV ? v : u;
    const int mh = w & 1, ch = w >> 1;         // mh: 32-row half; ch: 128-col half

    const size_t arow0 = (size_t)(m0 + mh * 32 + l15) * 256 + quad * 8;
    const size_t arow1 = arow0 + 16 * 256;

    f32x4 acc[2][8];
    #pragma unroll
    for (int mt = 0; mt < 2; ++mt)
        #pragma unroll
        for (int nt = 0; nt < 8; ++nt) acc[mt][nt] = (f32x4){0.f, 0.f, 0.f, 0.f};

    #pragma unroll
    for (int s = 0; s < 8; ++s) {
        const s16x8 ah0 = *(const s16x8*)(ehi + arow0 + s * 32);
        const s16x8 al0 = *(const s16x8*)(elo + arow0 + s * 32);
        const s16x8 ah1 = *(const s16x8*)(ehi + arow1 + s * 32);
        const s16x8 al1 = *(const s16x8*)(elo + arow1 + s * 32);
        #pragma unroll
        for (int nt = 0; nt < 8; ++nt) {
            const int n = ch * 128 + nt * 16 + l15;
            const size_t bo = (size_t)n * 256 + s * 32 + quad * 8;
            const s16x8 bh = *(const s16x8*)(Wh + bo);
            acc[0][nt] = __builtin_amdgcn_mfma_f32_16x16x32_bf16(ah0, bh, acc[0][nt], 0, 0, 0);
            acc[0][nt] = __builtin_amdgcn_mfma_f32_16x16x32_bf16(al0, bh, acc[0][nt], 0, 0, 0);
            acc[1][nt] = __builtin_amdgcn_mfma_f32_16x16x32_bf16(ah1, bh, acc[1][nt], 0, 0, 0);
            acc[1][nt] = __builtin_amdgcn_mfma_f32_16x16x32_bf16(al1, bh, acc[1][nt], 0, 0, 0);
        }
    }

    #pragma unroll
    for (int mt = 0; mt < 2; ++mt) {
        #pragma unroll
        for (int nt = 0; nt < 8; ++nt) {
            const int col = ch * 128 + nt * 16 + l15;
            const float bias = isV ? 0.f : gb1[col];
            #pragma unroll
            for (int r = 0; r < 4; ++r) {
                const int row = mh * 32 + mt * 16 + quad * 4 + r;
                out[(size_t)(m0 + row) * 256 + col] = acc[mt][nt][r] + bias;
            }
        }
    }
}

// ---------------------------------------------------------------------------
// Kernel 5: edge GEMM + max aggregation. Block = 8 points (64 edges), 4 waves;
// wave w = all 64 edges x cols w*64..+63. 2-pass split (A hi+lo trunc-split,
// B hi only). u rows staged ONCE in LDS (kills 8x-redundant u gathers);
// v loads software-pipelined a full k-step ahead of SPLITW.
// ---------------------------------------------------------------------------
__global__ __launch_bounds__(256)
void k_edge(const float* __restrict__ u, const float* __restrict__ v,
            const int* __restrict__ nidx,
            const ushort* __restrict__ g2h,
            const float* __restrict__ hb,
            float* __restrict__ part)
{
    __shared__ ushort Abuf[2][2][2304];   // [dbuf][hi/lo][edge*36+k], 18.4 KB
    __shared__ float ustage[2048];        // 8 pts x 256 k, 8 KB

    const int t = threadIdx.x, w = t >> 6, lane = t & 63;
    const int l15 = lane & 15, quad = lane >> 4;

    const int b = blockIdx.x;
    const int xcd = b & 7, rest = b >> 3;        // rest 0..511
    const int cell = xcd * 8 + (rest >> 6);      // 0..63
    const int pl0 = cell * NP + (rest & 63) * 8;

    // stage u rows once (coalesced, 8 floats per thread)
    {
        const int pt = t >> 5, kk = (t & 31) * 8;
        const float4 a = *(const float4*)(u + (size_t)(pl0 + pt) * 256 + kk);
        const float4 bq = *(const float4*)(u + (size_t)(pl0 + pt) * 256 + kk + 4);
        *(float4*)&ustage[pt * 256 + kk] = a;
        *(float4*)&ustage[pt * 256 + kk + 4] = bq;
    }

    const int se = t >> 2, kq = t & 3;
    const int upt = se >> 3;                     // point within block
    int svrow = nidx[(size_t)(pl0 + upt) * KNN + (se & 7)];
    if ((unsigned)svrow >= (unsigned)NTOT) svrow = 0;

    __syncthreads();                             // ustage visible

    float4 va, vb;

    #define LOADR(S)                                                             \
    {                                                                            \
        const int k0 = (S) * 32 + kq * 8;                                        \
        va = *(const float4*)(v + (size_t)svrow * 256 + k0);                     \
        vb = *(const float4*)(v + (size_t)svrow * 256 + k0 + 4);                 \
    }
    #define SPLITW(S, BUF)                                                       \
    {                                                                            \
        const int k0 = (S) * 32 + kq * 8;                                        \
        const float4 ua = *(const float4*)&ustage[upt * 256 + k0];               \
        const float4 ub = *(const float4*)&ustage[upt * 256 + k0 + 4];           \
        const float sv[8] = {                                                    \
            fmaxf(ua.x + va.x, 0.f), fmaxf(ua.y + va.y, 0.f),                    \
            fmaxf(ua.z + va.z, 0.f), fmaxf(ua.w + va.w, 0.f),                    \
            fmaxf(ub.x + vb.x, 0.f), fmaxf(ub.y + vb.y, 0.f),                    \
            fmaxf(ub.z + vb.z, 0.f), fmaxf(ub.w + vb.w, 0.f)};                   \
        union { uint2 q[2]; ushort us[8]; } th, tl;                              \
        _Pragma("unroll")                                                        \
        for (int j = 0; j < 8; ++j) { split2t(sv[j], th.us[j], tl.us[j]); }      \
        *(uint2*)&Abuf[BUF][0][se * 36 + kq * 8]     = th.q[0];                  \
        *(uint2*)&Abuf[BUF][0][se * 36 + kq * 8 + 4] = th.q[1];                  \
        *(uint2*)&Abuf[BUF][1][se * 36 + kq * 8]     = tl.q[0];                  \
        *(uint2*)&Abuf[BUF][1][se * 36 + kq * 8 + 4] = tl.q[1];                  \
    }

    f32x4 acc[4][4];
    #pragma unroll
    for (int mt = 0; mt < 4; ++mt)
        #pragma unroll
        for (int nt = 0; nt < 4; ++nt) acc[mt][nt] = (f32x4){0.f, 0.f, 0.f, 0.f};

    LOADR(0);
    SPLITW(0, 0);
    LOADR(1);
    for (int s = 0; s < 8; ++s) {
        __syncthreads();                      // buf[s&1] visible; buf[(s+1)&1] readers done
        if (s < 7) {
            SPLITW(s + 1, (s + 1) & 1);       // v regs resident; u from LDS
            if (s < 6) LOADR(s + 2);          // v latency hides under MFMAs
        }

        const int k0 = s * 32 + quad * 8;
        s16x8 ah[4], al[4];
        #pragma unroll
        for (int mt = 0; mt < 4; ++mt) {
            const int ao = (mt * 16 + l15) * 36 + quad * 8;
            union { uint2 q[2]; s16x8 v8; } Th, Tl;
            Th.q[0] = *(const uint2*)&Abuf[s & 1][0][ao];
            Th.q[1] = *(const uint2*)&Abuf[s & 1][0][ao + 4];
            Tl.q[0] = *(const uint2*)&Abuf[s & 1][1][ao];
            Tl.q[1] = *(const uint2*)&Abuf[s & 1][1][ao + 4];
            ah[mt] = Th.v8; al[mt] = Tl.v8;
        }
        #pragma unroll
        for (int nt = 0; nt < 4; ++nt) {
            const int n = w * 64 + nt * 16 + l15;
            const s16x8 bh = *(const s16x8*)(g2h + (size_t)n * 256 + k0);
            #pragma unroll
            for (int mt = 0; mt < 4; ++mt) {
                acc[mt][nt] = __builtin_amdgcn_mfma_f32_16x16x32_bf16(ah[mt], bh, acc[mt][nt], 0, 0, 0);
                acc[mt][nt] = __builtin_amdgcn_mfma_f32_16x16x32_bf16(al[mt], bh, acc[mt][nt], 0, 0, 0);
            }
        }
    }
    #undef LOADR
    #undef SPLITW

    const int slot = rest & 63;
    #pragma unroll
    for (int nt = 0; nt < 4; ++nt) {
        float rm = -3.4e38f;
        #pragma unroll
        for (int mt = 0; mt < 4; ++mt)
            rm = fmaxf(rm, fmaxf(fmaxf(acc[mt][nt][0], acc[mt][nt][1]),
                                 fmaxf(acc[mt][nt][2], acc[mt][nt][3])));
        rm = fmaxf(rm, __shfl_xor(rm, 16, 64));
        rm = fmaxf(rm, __shfl_xor(rm, 32, 64));
        if (quad == 0) {
            const int col = w * 64 + nt * 16 + l15;
            part[((size_t)cell * 64 + slot) * 256 + col] = rm + hb[col];
        }
    }
}

// ---------------------------------------------------------------------------
// Kernel 6: reduce 64 partial maxes per cell, final MLP (f32), L2 normalize.
// ---------------------------------------------------------------------------
__global__ __launch_bounds__(256)
void k_final(const float* __restrict__ part,
             const float* __restrict__ lW1, const float* __restrict__ lb1,
             const float* __restrict__ lW2, const float* __restrict__ lb2,
             float* __restrict__ out)
{
    __shared__ float pooled[256];
    __shared__ float hid[256];
    __shared__ float red[4];

    const int b = blockIdx.x;
    const int t = threadIdx.x;

    float m = -3.4e38f;
    for (int s = 0; s < 64; ++s)
        m = fmaxf(m, part[((size_t)b * 64 + s) * 256 + t]);
    pooled[t] = m;
    __syncthreads();

    float h = lb1[t];
    for (int k = 0; k < 256; k += 4) {
        #pragma unroll
        for (int kk = 0; kk < 4; ++kk)
            h += pooled[k + kk] * lW1[(k + kk) * 256 + t];
    }
    hid[t] = fmaxf(h, 0.f);
    __syncthreads();

    float o = lb2[t];
    for (int k = 0; k < 256; k += 4) {
        #pragma unroll
        for (int kk = 0; kk < 4; ++kk)
            o += hid[k + kk] * lW2[(k + kk) * 256 + t];
    }

    float ss = o * o;
    #pragma unroll
    for (int s = 32; s > 0; s >>= 1) ss += __shfl_down(ss, s, 64);
    if ((t & 63) == 0) red[t >> 6] = ss;
    __syncthreads();
    const float tot = red[0] + red[1] + red[2] + red[3];
    const float rn = 1.f / fmaxf(sqrtf(tot), 1e-12f);
    out[b * 256 + t] = o * rn;
}

// ---------------------------------------------------------------------------
extern "C" void kernel_launch(void* const* d_in, const int* in_sizes, int n_in,
                              void* d_out, int out_size, void* d_ws, size_t ws_size,
                              hipStream_t stream)
{
    (void)n_in; (void)out_size; (void)ws_size;

    const float* class_table = (const float*)d_in[0];
    const float* cW1 = (const float*)d_in[1];
    const float* cb1 = (const float*)d_in[2];
    const float* cW2 = (const float*)d_in[3];
    const float* cb2 = (const float*)d_in[4];
    const float* pW1 = (const float*)d_in[5];
    const float* pb1 = (const float*)d_in[6];
    const float* pW2 = (const float*)d_in[7];
    const float* pb2 = (const float*)d_in[8];
    const float* mW  = (const float*)d_in[9];
    const float* mb  = (const float*)d_in[10];
    const float* gW1 = (const float*)d_in[11];
    const float* gb1 = (const float*)d_in[12];
    const float* g_gamma = (const float*)d_in[13];
    const float* g_beta  = (const float*)d_in[14];
    const float* gW2 = (const float*)d_in[15];
    const float* gb2 = (const float*)d_in[16];
    const float* lW1 = (const float*)d_in[17];
    const float* lb1 = (const float*)d_in[18];
    const float* lW2 = (const float*)d_in[19];
    const float* lb2 = (const float*)d_in[20];
    const float* positions = (const float*)d_in[21];
    const float* colors    = (const float*)d_in[22];
    const int*  cls        = (const int*)d_in[23];

    const int cstride = (in_sizes[23] == 2 * NTOT) ? 2 : 1;

    // workspace layout (bytes), total ~174 MB (ws_size ~268 MB).
    char* base = (char*)d_ws;
    float*   part   = (float*)(base + 0);               //   4,194,304
    ushort*  Wdh    = (ushort*)(base + 4194304);
    ushort*  Wdl    = (ushort*)(base + 4325376);
    ushort*  Wbh    = (ushort*)(base + 4456448);
    ushort*  Wbl    = (ushort*)(base + 4587520);
    ushort*  g2h    = (ushort*)(base + 4718592);
    ushort*  g2l    = (ushort*)(base + 4849664);
    float*   hb     = (float*)(base + 4980736);
    ushort*  cW2Th  = (ushort*)(base + 4981760);
    ushort*  cW2Tl  = (ushort*)(base + 5014528);
    ushort*  pW2Th  = (ushort*)(base + 5047296);
    ushort*  pW2Tl  = (ushort*)(base + 5080064);
    ushort*  WcTh   = (ushort*)(base + 5112832);
    ushort*  WcTl   = (ushort*)(base + 5145600);
    ushort*  WpTh   = (ushort*)(base + 5178368);
    ushort*  WpTl   = (ushort*)(base + 5211136);
    float*   classMn= (float*)(base + 5243904);
    float*   cbM    = (float*)(base + 5275648);
    float*   pbM    = (float*)(base + 5276672);
    int*     nidx   = (int*)(base + 5277696);           //   1,048,576
    float*   sqn    = (float*)(base + 6326272);         //     131,072
    ushort*  ehi    = (ushort*)(base + 6457344);        //  16,777,216
    ushort*  elo    = (ushort*)(base + 23234560);       //  16,777,216
    float*   dist   = (float*)(base + 40011776);        //  67,108,864
    float*   v      = (float*)(base + 107120640);       //  33,554,432
    float*   u      = (float*)(base + 140675072);       //  33,554,432
    float* out = (float*)d_out;

    k_cvt<<<897, 256, 0, stream>>>(gW1, gW2, g_gamma, g_beta, gb2, cW2, pW2,
                                   Wdh, Wdl, Wbh, Wbl, g2h, g2l, hb,
                                   cW2Th, cW2Tl, pW2Th, pW2Tl);
    k_fold<<<130, 256, 0, stream>>>(cW2, pW2, cb2, pb2, mW,
                                    WcTh, WcTl, WpTh, WpTl, cbM, pbM);
    k_cls<<<31, 256, 0, stream>>>(class_table, mW, classMn);

    k_embed<<<NTOT / 16, 256, 0, stream>>>(classMn, cW1, cb1, cb2, pW1, pb1, pb2,
                                           mb, cW2Th, cW2Tl, pW2Th, pW2Tl,
                                           WcTh, WcTl, WpTh, WpTl, cbM, pbM,
                                           positions, colors, cls, cstride,
                                           ehi, elo, sqn);
    k_gram<<<NB * 32, 256, 0, stream>>>(ehi, elo, sqn, dist);
    k_select<<<NTOT / 4, 256, 0, stream>>>(dist, nidx);
    k_uv<<<2 * NTOT / 64, 256, 0, stream>>>(ehi, elo, Wdh, Wbh, gb1, u, v);
    k_edge<<<NTOT / 8, 256, 0, stream>>>(u, v, nidx, g2h, hb, part);
    k_final<<<NB, 256, 0, stream>>>(part, lW1, lb1, lW2, lb2, out);
}

// Round 16
// 515.538 us; speedup vs baseline: 1.3743x; 1.0342x over previous
//
#include <hip/hip_runtime.h>

#define EDIM 256
#define KNN 8
#define NB 64
#define NP 512
#define NTOT (NB * NP)

typedef short s16x8 __attribute__((ext_vector_type(8)));
typedef float f32x4 __attribute__((ext_vector_type(4)));
typedef unsigned short ushort;

__device__ __forceinline__ ushort f2b(float f) {
    unsigned u = __float_as_uint(f);
    u = (u + 0x7fffu + ((u >> 16) & 1u)) >> 16;   // RNE
    return (ushort)u;
}
__device__ __forceinline__ float b2f(ushort h) {
    return __uint_as_float(((unsigned)h) << 16);
}
__device__ __forceinline__ void split2(float x, ushort& h, ushort& l) {
    h = f2b(x);
    l = f2b(x - b2f(h));
}
// truncation split (edge hot path): pair error ~2^-16 relative, fewer VALU
__device__ __forceinline__ ushort f2bt(float f) {
    return (ushort)(__float_as_uint(f) >> 16);
}
__device__ __forceinline__ void split2t(float x, ushort& h, ushort& l) {
    h = f2bt(x);
    l = f2bt(x - b2f(h));
}

// ---------------------------------------------------------------------------
// Kernel 0a: weight prep -> transposed bf16 hi/lo pairs.
// ---------------------------------------------------------------------------
__global__ __launch_bounds__(256)
void k_cvt(const float* __restrict__ gW1, const float* __restrict__ gW2,
           const float* __restrict__ g_gamma, const float* __restrict__ g_beta,
           const float* __restrict__ gb2,
           const float* __restrict__ cW2, const float* __restrict__ pW2,
           ushort* __restrict__ Wdh, ushort* __restrict__ Wdl,
           ushort* __restrict__ Wbh, ushort* __restrict__ Wbl,
           ushort* __restrict__ g2h, ushort* __restrict__ g2l,
           float* __restrict__ hb,
           ushort* __restrict__ cW2Th, ushort* __restrict__ cW2Tl,
           ushort* __restrict__ pW2Th, ushort* __restrict__ pW2Tl)
{
    const int gid = blockIdx.x * 256 + threadIdx.x;
    ushort h, l;
    if (gid < 65536) {
        const int n = gid >> 8, k = gid & 255;
        split2(gW1[k * 256 + n] - gW1[(k + 256) * 256 + n], h, l);
        Wdh[gid] = h; Wdl[gid] = l;
    } else if (gid < 131072) {
        const int i = gid - 65536, n = i >> 8, k = i & 255;
        split2(gW1[(k + 256) * 256 + n], h, l);
        Wbh[i] = h; Wbl[i] = l;
    } else if (gid < 196608) {
        const int i = gid - 131072, n = i >> 8, k = i & 255;
        split2(g_gamma[k] * gW2[k * 256 + n], h, l);
        g2h[i] = h; g2l[i] = l;
    } else if (gid < 196864) {
        const int n = gid - 196608;
        float s = gb2[n];
        for (int k = 0; k < 256; ++k) s += g_beta[k] * gW2[k * 256 + n];
        hb[n] = s;
    } else if (gid < 213248) {
        const int i = gid - 196864, n = i >> 6, k = i & 63;
        split2(cW2[k * 256 + n], h, l);
        cW2Th[i] = h; cW2Tl[i] = l;
    } else if (gid < 229632) {
        const int i = gid - 213248, n = i >> 6, k = i & 63;
        split2(pW2[k * 256 + n], h, l);
        pW2Th[i] = h; pW2Tl[i] = l;
    }
}

// ---------------------------------------------------------------------------
// Kernel 0b: fold merge GEMM into the MLP weights (linearity).
// ---------------------------------------------------------------------------
__global__ __launch_bounds__(256)
void k_fold(const float* __restrict__ cW2, const float* __restrict__ pW2,
            const float* __restrict__ cb2, const float* __restrict__ pb2,
            const float* __restrict__ mW,
            ushort* __restrict__ WcTh, ushort* __restrict__ WcTl,
            ushort* __restrict__ WpTh, ushort* __restrict__ WpTl,
            float* __restrict__ cbM, float* __restrict__ pbM)
{
    const int gid = blockIdx.x * 256 + threadIdx.x;
    ushort h, l;
    if (gid < 16384) {
        const int j = gid >> 8, n = gid & 255;
        float s = 0.f;
        for (int k = 0; k < 256; ++k) s += cW2[j * 256 + k] * mW[(256 + k) * 256 + n];
        split2(s, h, l);
        WcTh[n * 64 + j] = h; WcTl[n * 64 + j] = l;
    } else if (gid < 32768) {
        const int i = gid - 16384, j = i >> 8, n = i & 255;
        float s = 0.f;
        for (int k = 0; k < 256; ++k) s += pW2[j * 256 + k] * mW[(512 + k) * 256 + n];
        split2(s, h, l);
        WpTh[n * 64 + j] = h; WpTl[n * 64 + j] = l;
    } else if (gid < 33024) {
        const int n = gid - 32768;
        float s = 0.f;
        for (int k = 0; k < 256; ++k) s += cb2[k] * mW[(256 + k) * 256 + n];
        cbM[n] = s;
    } else if (gid < 33280) {
        const int n = gid - 33024;
        float s = 0.f;
        for (int k = 0; k < 256; ++k) s += pb2[k] * mW[(512 + k) * 256 + n];
        pbM[n] = s;
    }
}

// ---------------------------------------------------------------------------
// Kernel 0c: classMn[c] = (class_table[c] / ||class_table[c]||) @ M0.
// ---------------------------------------------------------------------------
__global__ __launch_bounds__(256)
void k_cls(const float* __restrict__ ct, const float* __restrict__ mW,
           float* __restrict__ classMn)
{
    __shared__ float ctn[256];
    __shared__ float red[4];
    const int c = blockIdx.x, t = threadIdx.x;
    const float v = ct[c * 256 + t];
    float ss = v * v;
    #pragma unroll
    for (int s = 32; s > 0; s >>= 1) ss += __shfl_down(ss, s, 64);
    if ((t & 63) == 0) red[t >> 6] = ss;
    __syncthreads();
    const float tot = red[0] + red[1] + red[2] + red[3];
    const float r = 1.f / fmaxf(sqrtf(tot), 1e-12f);
    ctn[t] = v * r;
    __syncthreads();
    float s = 0.f;
    for (int k = 0; k < 256; ++k) s += ctn[k] * mW[k * 256 + t];
    classMn[c * 256 + t] = s;
}

// ---------------------------------------------------------------------------
// Kernel 1: embeddings via folded GEMMs. 16 obj/block, full problem (2048).
// ---------------------------------------------------------------------------
__global__ __launch_bounds__(256)
void k_embed(const float* __restrict__ classMn,
             const float* __restrict__ cW1, const float* __restrict__ cb1,
             const float* __restrict__ cb2,
             const float* __restrict__ pW1, const float* __restrict__ pb1,
             const float* __restrict__ pb2,
             const float* __restrict__ mb,
             const ushort* __restrict__ cW2Th, const ushort* __restrict__ cW2Tl,
             const ushort* __restrict__ pW2Th, const ushort* __restrict__ pW2Tl,
             const ushort* __restrict__ WcTh, const ushort* __restrict__ WcTl,
             const ushort* __restrict__ WpTh, const ushort* __restrict__ WpTl,
             const float* __restrict__ cbM, const float* __restrict__ pbM,
             const float* __restrict__ positions, const float* __restrict__ colors,
             const int* __restrict__ cls, const int cstride,
             ushort* __restrict__ ehi, ushort* __restrict__ elo,
             float* __restrict__ sqn)
{
    __shared__ __align__(16) ushort Ahc[16 * 72];
    __shared__ __align__(16) ushort Alc[16 * 72];
    __shared__ __align__(16) ushort Ahp[16 * 72];
    __shared__ __align__(16) ushort Alp[16 * 72];
    __shared__ float sqc[16][4], sqp_[16][4], sqe[16][4];

    const int t = threadIdx.x, w = t >> 6, lane = t & 63;
    const int l15 = lane & 15, quad = lane >> 4;
    const int obase = blockIdx.x * 16;

    {
        const int o = lane >> 4;
        const int objl = w * 4 + o;
        const int gobj = obase + objl;
        const float c0 = colors[gobj * 3], c1 = colors[gobj * 3 + 1], c2 = colors[gobj * 3 + 2];
        const float q0 = positions[gobj * 3], q1 = positions[gobj * 3 + 1], q2 = positions[gobj * 3 + 2];
        const int u0 = (lane & 15) * 4;
        #pragma unroll
        for (int uu = 0; uu < 4; ++uu) {
            const int u = u0 + uu;
            const float hc = fmaxf(cb1[u] + c0 * cW1[u] + c1 * cW1[64 + u] + c2 * cW1[128 + u], 0.f);
            const float hp = fmaxf(pb1[u] + q0 * pW1[u] + q1 * pW1[64 + u] + q2 * pW1[128 + u], 0.f);
            ushort h, l;
            split2(hc, h, l); Ahc[objl * 72 + u] = h; Alc[objl * 72 + u] = l;
            split2(hp, h, l); Ahp[objl * 72 + u] = h; Alp[objl * 72 + u] = l;
        }
    }
    __syncthreads();

    f32x4 aco[4], ape[4];
    #pragma unroll
    for (int nt = 0; nt < 4; ++nt) { aco[nt] = (f32x4){0.f,0.f,0.f,0.f}; ape[nt] = (f32x4){0.f,0.f,0.f,0.f}; }

    #pragma unroll
    for (int kt = 0; kt < 2; ++kt) {
        const int ao = l15 * 72 + kt * 32 + quad * 8;
        const s16x8 ahc = *(const s16x8*)&Ahc[ao];
        const s16x8 alc = *(const s16x8*)&Alc[ao];
        const s16x8 ahp = *(const s16x8*)&Ahp[ao];
        const s16x8 alp = *(const s16x8*)&Alp[ao];
        #pragma unroll
        for (int nt = 0; nt < 4; ++nt) {
            const int n = w * 64 + nt * 16 + l15;
            const size_t bo = (size_t)n * 64 + kt * 32 + quad * 8;
            const s16x8 cbh = *(const s16x8*)(cW2Th + bo);
            const s16x8 cbl = *(const s16x8*)(cW2Tl + bo);
            const s16x8 pbh = *(const s16x8*)(pW2Th + bo);
            const s16x8 pbl = *(const s16x8*)(pW2Tl + bo);
            aco[nt] = __builtin_amdgcn_mfma_f32_16x16x32_bf16(ahc, cbh, aco[nt], 0, 0, 0);
            ape[nt] = __builtin_amdgcn_mfma_f32_16x16x32_bf16(ahp, pbh, ape[nt], 0, 0, 0);
            aco[nt] = __builtin_amdgcn_mfma_f32_16x16x32_bf16(alc, cbh, aco[nt], 0, 0, 0);
            ape[nt] = __builtin_amdgcn_mfma_f32_16x16x32_bf16(alp, pbh, ape[nt], 0, 0, 0);
            aco[nt] = __builtin_amdgcn_mfma_f32_16x16x32_bf16(ahc, cbl, aco[nt], 0, 0, 0);
            ape[nt] = __builtin_amdgcn_mfma_f32_16x16x32_bf16(ahp, pbl, ape[nt], 0, 0, 0);
        }
    }

    float sc[4] = {0.f,0.f,0.f,0.f}, sp[4] = {0.f,0.f,0.f,0.f};
    #pragma unroll
    for (int nt = 0; nt < 4; ++nt) {
        const int col = w * 64 + nt * 16 + l15;
        const float cbv = cb2[col], pbv = pb2[col];
        #pragma unroll
        for (int r = 0; r < 4; ++r) {
            const float co = aco[nt][r] + cbv;
            const float pe = ape[nt][r] + pbv;
            sc[r] += co * co;
            sp[r] += pe * pe;
        }
    }
    #pragma unroll
    for (int s = 8; s > 0; s >>= 1) {
        #pragma unroll
        for (int r = 0; r < 4; ++r) {
            sc[r] += __shfl_xor(sc[r], s, 64);
            sp[r] += __shfl_xor(sp[r], s, 64);
        }
    }
    if (l15 == 0) {
        #pragma unroll
        for (int r = 0; r < 4; ++r) { sqc[quad * 4 + r][w] = sc[r]; sqp_[quad * 4 + r][w] = sp[r]; }
    }
    __syncthreads();

    float rco[4], rpe[4];
    #pragma unroll
    for (int r = 0; r < 4; ++r) {
        const int row = quad * 4 + r;
        rco[r] = 1.f / fmaxf(sqrtf(sqc[row][0] + sqc[row][1] + sqc[row][2] + sqc[row][3]), 1e-12f);
        rpe[r] = 1.f / fmaxf(sqrtf(sqp_[row][0] + sqp_[row][1] + sqp_[row][2] + sqp_[row][3]), 1e-12f);
    }

    f32x4 ac[4], ap[4];
    #pragma unroll
    for (int nt = 0; nt < 4; ++nt) { ac[nt] = (f32x4){0.f,0.f,0.f,0.f}; ap[nt] = (f32x4){0.f,0.f,0.f,0.f}; }

    #pragma unroll
    for (int kt = 0; kt < 2; ++kt) {
        const int ao = l15 * 72 + kt * 32 + quad * 8;
        const s16x8 ahc = *(const s16x8*)&Ahc[ao];
        const s16x8 alc = *(const s16x8*)&Alc[ao];
        const s16x8 ahp = *(const s16x8*)&Ahp[ao];
        const s16x8 alp = *(const s16x8*)&Alp[ao];
        #pragma unroll
        for (int nt = 0; nt < 4; ++nt) {
            const int n = w * 64 + nt * 16 + l15;
            const size_t bo = (size_t)n * 64 + kt * 32 + quad * 8;
            const s16x8 cbh = *(const s16x8*)(WcTh + bo);
            const s16x8 cbl = *(const s16x8*)(WcTl + bo);
            const s16x8 pbh = *(const s16x8*)(WpTh + bo);
            const s16x8 pbl = *(const s16x8*)(WpTl + bo);
            ac[nt] = __builtin_amdgcn_mfma_f32_16x16x32_bf16(ahc, cbh, ac[nt], 0, 0, 0);
            ap[nt] = __builtin_amdgcn_mfma_f32_16x16x32_bf16(ahp, pbh, ap[nt], 0, 0, 0);
            ac[nt] = __builtin_amdgcn_mfma_f32_16x16x32_bf16(alc, cbh, ac[nt], 0, 0, 0);
            ap[nt] = __builtin_amdgcn_mfma_f32_16x16x32_bf16(alp, pbh, ap[nt], 0, 0, 0);
            ac[nt] = __builtin_amdgcn_mfma_f32_16x16x32_bf16(ahc, cbl, ac[nt], 0, 0, 0);
            ap[nt] = __builtin_amdgcn_mfma_f32_16x16x32_bf16(ahp, pbl, ap[nt], 0, 0, 0);
        }
    }

    int ci[4];
    #pragma unroll
    for (int r = 0; r < 4; ++r) {
        const int gobj = obase + quad * 4 + r;
        int c = cls[(size_t)gobj * cstride];
        if ((unsigned)c > 30u) c = 0;
        ci[r] = c;
    }

    float rp[4] = {0.f,0.f,0.f,0.f};
    #pragma unroll
    for (int nt = 0; nt < 4; ++nt) {
        const int col = w * 64 + nt * 16 + l15;
        const float mbv = mb[col], cbMv = cbM[col], pbMv = pbM[col];
        #pragma unroll
        for (int r = 0; r < 4; ++r) {
            const int row = quad * 4 + r;
            const float e = classMn[ci[r] * 256 + col]
                          + rco[r] * (ac[nt][r] + cbMv)
                          + rpe[r] * (ap[nt][r] + pbMv) + mbv;
            ushort h, l;
            split2(e, h, l);
            ehi[(size_t)(obase + row) * 256 + col] = h;
            elo[(size_t)(obase + row) * 256 + col] = l;
            rp[r] += e * e;
        }
    }
    #pragma unroll
    for (int s = 8; s > 0; s >>= 1) {
        #pragma unroll
        for (int r = 0; r < 4; ++r) rp[r] += __shfl_xor(rp[r], s, 64);
    }
    if (l15 == 0) {
        #pragma unroll
        for (int r = 0; r < 4; ++r) sqe[quad * 4 + r][w] = rp[r];
    }
    __syncthreads();
    if (t < 16) sqn[obase + t] = sqe[t][0] + sqe[t][1] + sqe[t][2] + sqe[t][3];
}

// ---------------------------------------------------------------------------
// Kernel 2: Gram/distance via 3-pass split MFMA, 128x64 tile per block.
// ---------------------------------------------------------------------------
__global__ __launch_bounds__(256)
void k_gram(const ushort* __restrict__ ehi, const ushort* __restrict__ elo,
            const float* __restrict__ sqn, float* __restrict__ dist)
{
    const int t = threadIdx.x, w = t >> 6, lane = t & 63;
    const int l15 = lane & 15, quad = lane >> 4;
    const int xcd = blockIdx.x & 7, rest = blockIdx.x >> 3;   // rest 0..255
    const int b_local = xcd * 8 + (rest >> 5);                // 0..63
    const int tile = rest & 31;
    const int p0 = (tile >> 3) * 128, q0 = (tile & 7) * 64;
    const size_t cb = (size_t)b_local * NP;

    f32x4 acc[2][4];
    #pragma unroll
    for (int sub = 0; sub < 2; ++sub)
        #pragma unroll
        for (int nt = 0; nt < 4; ++nt) acc[sub][nt] = (f32x4){0.f, 0.f, 0.f, 0.f};

    #pragma unroll
    for (int s = 0; s < 8; ++s) {
        s16x8 ah[2], al[2];
        #pragma unroll
        for (int sub = 0; sub < 2; ++sub) {
            const size_t ao = (cb + p0 + sub * 64 + 16 * w + l15) * 256 + s * 32 + quad * 8;
            ah[sub] = *(const s16x8*)(ehi + ao);
            al[sub] = *(const s16x8*)(elo + ao);
        }
        #pragma unroll
        for (int nt = 0; nt < 4; ++nt) {
            const size_t bo = (cb + q0 + nt * 16 + l15) * 256 + s * 32 + quad * 8;
            const s16x8 bh = *(const s16x8*)(ehi + bo);
            const s16x8 bl = *(const s16x8*)(elo + bo);
            #pragma unroll
            for (int sub = 0; sub < 2; ++sub) {
                acc[sub][nt] = __builtin_amdgcn_mfma_f32_16x16x32_bf16(ah[sub], bh, acc[sub][nt], 0, 0, 0);
                acc[sub][nt] = __builtin_amdgcn_mfma_f32_16x16x32_bf16(al[sub], bh, acc[sub][nt], 0, 0, 0);
                acc[sub][nt] = __builtin_amdgcn_mfma_f32_16x16x32_bf16(ah[sub], bl, acc[sub][nt], 0, 0, 0);
            }
        }
    }

    #pragma unroll
    for (int sub = 0; sub < 2; ++sub) {
        float sqp[4];
        #pragma unroll
        for (int r = 0; r < 4; ++r)
            sqp[r] = sqn[cb + p0 + sub * 64 + 16 * w + quad * 4 + r];
        #pragma unroll
        for (int nt = 0; nt < 4; ++nt) {
            const int colq = q0 + nt * 16 + l15;
            const float sq_q = sqn[cb + colq];
            #pragma unroll
            for (int r = 0; r < 4; ++r) {
                const int rowp = p0 + sub * 64 + 16 * w + quad * 4 + r;
                dist[(cb + rowp) * NP + colq] = (sqp[r] + sq_q) - 2.f * acc[sub][nt][r];
            }
        }
    }
}

// ---------------------------------------------------------------------------
// Kernel 3: top-8 smallest per point (ties -> lowest index). One wave/point.
// ---------------------------------------------------------------------------
__global__ __launch_bounds__(256)
void k_select(const float* __restrict__ dist, int* __restrict__ nidx)
{
    const int wv = threadIdx.x >> 6, lane = threadIdx.x & 63;
    const int xcd = blockIdx.x & 7, rest = blockIdx.x >> 3;   // rest 0..1023
    const int cell = xcd * 8 + (rest >> 7);                   // 0..63
    const int p = cell * NP + (rest & 127) * 4 + wv;          // global point
    const float* row = dist + (size_t)p * NP;

    float d[8];
    {
        const float4 va = *(const float4*)(row + lane * 8);
        const float4 vb = *(const float4*)(row + lane * 8 + 4);
        d[0] = va.x; d[1] = va.y; d[2] = va.z; d[3] = va.w;
        d[4] = vb.x; d[5] = vb.y; d[6] = vb.z; d[7] = vb.w;
    }

    for (int r = 0; r < KNN; ++r) {
        float bd = d[0]; int bi = 0;
        #pragma unroll
        for (int i = 1; i < 8; ++i)
            if (d[i] < bd) { bd = d[i]; bi = i; }   // strict < keeps lowest i on tie
        int bq = lane * 8 + bi;
        #pragma unroll
        for (int s = 32; s > 0; s >>= 1) {
            const float od = __shfl_down(bd, s, 64);
            const int oq = __shfl_down(bq, s, 64);
            if (od < bd || (od == bd && oq < bq)) { bd = od; bq = oq; }
        }
        const int win = __shfl(bq, 0, 64);
        if (lane == 0) nidx[(size_t)p * KNN + r] = ((p >> 9) << 9) | win;
        if ((win >> 3) == lane) {
            const int wi = win & 7;
            #pragma unroll
            for (int i = 0; i < 8; ++i) if (wi == i) d[i] = 3.4e38f;
        }
    }
}

// ---------------------------------------------------------------------------
// Kernel 4: u = x@Wd+gb1, v = x@Wb via 2-pass split MFMA (A hi+lo, B hi only).
// 64 points/block: wave = 2 m-frags x 128 cols.
// ---------------------------------------------------------------------------
__global__ __launch_bounds__(256)
void k_uv(const ushort* __restrict__ ehi, const ushort* __restrict__ elo,
          const ushort* __restrict__ Wdh, const ushort* __restrict__ Wbh,
          const float* __restrict__ gb1,
          float* __restrict__ u, float* __restrict__ v)
{
    const int t = threadIdx.x, w = t >> 6, lane = t & 63;
    const int l15 = lane & 15, quad = lane >> 4;
    const int isV = blockIdx.x >> 9;           // 1024 blocks total
    const int m0 = (blockIdx.x & 511) * 64;
    const ushort* Wh = isV ? Wbh : Wdh;
    float* out = isV ? v : u;
    const int mh = w & 1, ch = w >> 1;

    const size_t arow0 = (size_t)(m0 + mh * 32 + l15) * 256 + quad * 8;
    const size_t arow1 = arow0 + 16 * 256;

    f32x4 acc[2][8];
    #pragma unroll
    for (int mt = 0; mt < 2; ++mt)
        #pragma unroll
        for (int nt = 0; nt < 8; ++nt) acc[mt][nt] = (f32x4){0.f, 0.f, 0.f, 0.f};

    #pragma unroll
    for (int s = 0; s < 8; ++s) {
        const s16x8 ah0 = *(const s16x8*)(ehi + arow0 + s * 32);
        const s16x8 al0 = *(const s16x8*)(elo + arow0 + s * 32);
        const s16x8 ah1 = *(const s16x8*)(ehi + arow1 + s * 32);
        const s16x8 al1 = *(const s16x8*)(elo + arow1 + s * 32);
        #pragma unroll
        for (int nt = 0; nt < 8; ++nt) {
            const int n = ch * 128 + nt * 16 + l15;
            const size_t bo = (size_t)n * 256 + s * 32 + quad * 8;
            const s16x8 bh = *(const s16x8*)(Wh + bo);
            acc[0][nt] = __builtin_amdgcn_mfma_f32_16x16x32_bf16(ah0, bh, acc[0][nt], 0, 0, 0);
            acc[0][nt] = __builtin_amdgcn_mfma_f32_16x16x32_bf16(al0, bh, acc[0][nt], 0, 0, 0);
            acc[1][nt] = __builtin_amdgcn_mfma_f32_16x16x32_bf16(ah1, bh, acc[1][nt], 0, 0, 0);
            acc[1][nt] = __builtin_amdgcn_mfma_f32_16x16x32_bf16(al1, bh, acc[1][nt], 0, 0, 0);
        }
    }

    #pragma unroll
    for (int mt = 0; mt < 2; ++mt) {
        #pragma unroll
        for (int nt = 0; nt < 8; ++nt) {
            const int col = ch * 128 + nt * 16 + l15;
            const float bias = isV ? 0.f : gb1[col];
            #pragma unroll
            for (int r = 0; r < 4; ++r) {
                const int row = mh * 32 + mt * 16 + quad * 4 + r;
                out[(size_t)(m0 + row) * 256 + col] = acc[mt][nt][r] + bias;
            }
        }
    }
}

// ---------------------------------------------------------------------------
// Kernel 5: edge GEMM + max aggregation. Block = 8 points (64 edges), 4 waves;
// wave w = all 64 edges x cols w*64..+63. 2-pass split (A trunc-split hi+lo,
// B hi only). DEEP pipeline: v global loads 3 register-sets deep (~2 k-steps
// of MFMA+barrier cover for HBM-latency gathers); u LDS reads prefetched one
// step ahead. Post-barrier path is pure VALU+ds_write on resident registers.
// ---------------------------------------------------------------------------
__global__ __launch_bounds__(256)
void k_edge(const float* __restrict__ u, const float* __restrict__ v,
            const int* __restrict__ nidx,
            const ushort* __restrict__ g2h,
            const float* __restrict__ hb,
            float* __restrict__ part)
{
    __shared__ ushort Abuf[2][2][2304];   // [dbuf][hi/lo][edge*36+k], 18.4 KB
    __shared__ float ustage[2048];        // 8 pts x 256 k, 8 KB

    const int t = threadIdx.x, w = t >> 6, lane = t & 63;
    const int l15 = lane & 15, quad = lane >> 4;

    const int b = blockIdx.x;
    const int xcd = b & 7, rest = b >> 3;        // rest 0..511
    const int cell = xcd * 8 + (rest >> 6);      // 0..63
    const int pl0 = cell * NP + (rest & 63) * 8;

    // stage u rows once (coalesced, 8 floats per thread)
    {
        const int pt = t >> 5, kk = (t & 31) * 8;
        const float4 a = *(const float4*)(u + (size_t)(pl0 + pt) * 256 + kk);
        const float4 bq = *(const float4*)(u + (size_t)(pl0 + pt) * 256 + kk + 4);
        *(float4*)&ustage[pt * 256 + kk] = a;
        *(float4*)&ustage[pt * 256 + kk + 4] = bq;
    }

    const int se = t >> 2, kq = t & 3;
    const int upt = se >> 3;                     // point within block
    int svrow = nidx[(size_t)(pl0 + upt) * KNN + (se & 7)];
    if ((unsigned)svrow >= (unsigned)NTOT) svrow = 0;

    __syncthreads();                             // ustage visible

    float4 vr[3][2];                             // 3-set v pipeline
    float4 ur[2][2];                             // 2-set u (LDS) pipeline

    #define VLOAD(S)                                                             \
    {                                                                            \
        const int k0 = (S) * 32 + kq * 8;                                        \
        vr[(S) % 3][0] = *(const float4*)(v + (size_t)svrow * 256 + k0);         \
        vr[(S) % 3][1] = *(const float4*)(v + (size_t)svrow * 256 + k0 + 4);     \
    }
    #define ULOAD(S)                                                             \
    {                                                                            \
        const int k0 = (S) * 32 + kq * 8;                                        \
        ur[(S) & 1][0] = *(const float4*)&ustage[upt * 256 + k0];                \
        ur[(S) & 1][1] = *(const float4*)&ustage[upt * 256 + k0 + 4];            \
    }
    #define SPLITW(S, BUF)                                                       \
    {                                                                            \
        const float4 ua = ur[(S) & 1][0], ub = ur[(S) & 1][1];                   \
        const float4 va = vr[(S) % 3][0], vb = vr[(S) % 3][1];                   \
        const float sv[8] = {                                                    \
            fmaxf(ua.x + va.x, 0.f), fmaxf(ua.y + va.y, 0.f),                    \
            fmaxf(ua.z + va.z, 0.f), fmaxf(ua.w + va.w, 0.f),                    \
            fmaxf(ub.x + vb.x, 0.f), fmaxf(ub.y + vb.y, 0.f),                    \
            fmaxf(ub.z + vb.z, 0.f), fmaxf(ub.w + vb.w, 0.f)};                   \
        union { uint2 q[2]; ushort us[8]; } th, tl;                              \
        _Pragma("unroll")                                                        \
        for (int j = 0; j < 8; ++j) { split2t(sv[j], th.us[j], tl.us[j]); }      \
        *(uint2*)&Abuf[BUF][0][se * 36 + kq * 8]     = th.q[0];                  \
        *(uint2*)&Abuf[BUF][0][se * 36 + kq * 8 + 4] = th.q[1];                  \
        *(uint2*)&Abuf[BUF][1][se * 36 + kq * 8]     = tl.q[0];                  \
        *(uint2*)&Abuf[BUF][1][se * 36 + kq * 8 + 4] = tl.q[1];                  \
    }

    f32x4 acc[4][4];
    #pragma unroll
    for (int mt = 0; mt < 4; ++mt)
        #pragma unroll
        for (int nt = 0; nt < 4; ++nt) acc[mt][nt] = (f32x4){0.f, 0.f, 0.f, 0.f};

    VLOAD(0); VLOAD(1); VLOAD(2);
    ULOAD(0);
    SPLITW(0, 0);
    ULOAD(1);

    #pragma unroll
    for (int s = 0; s < 8; ++s) {
        __syncthreads();                      // buf[s&1] visible; buf[(s+1)&1] readers done
        if (s < 7) {
            SPLITW(s + 1, (s + 1) & 1);       // all operands register-resident
            if (s < 6) ULOAD(s + 2);
            if (s < 5) VLOAD(s + 3);          // ~2 k-steps of latency cover
        }

        const int k0 = s * 32 + quad * 8;
        s16x8 ah[4], al[4];
        #pragma unroll
        for (int mt = 0; mt < 4; ++mt) {
            const int ao = (mt * 16 + l15) * 36 + quad * 8;
            union { uint2 q[2]; s16x8 v8; } Th, Tl;
            Th.q[0] = *(const uint2*)&Abuf[s & 1][0][ao];
            Th.q[1] = *(const uint2*)&Abuf[s & 1][0][ao + 4];
            Tl.q[0] = *(const uint2*)&Abuf[s & 1][1][ao];
            Tl.q[1] = *(const uint2*)&Abuf[s & 1][1][ao + 4];
            ah[mt] = Th.v8; al[mt] = Tl.v8;
        }
        #pragma unroll
        for (int nt = 0; nt < 4; ++nt) {
            const int n = w * 64 + nt * 16 + l15;
            const s16x8 bh = *(const s16x8*)(g2h + (size_t)n * 256 + k0);
            #pragma unroll
            for (int mt = 0; mt < 4; ++mt) {
                acc[mt][nt] = __builtin_amdgcn_mfma_f32_16x16x32_bf16(ah[mt], bh, acc[mt][nt], 0, 0, 0);
                acc[mt][nt] = __builtin_amdgcn_mfma_f32_16x16x32_bf16(al[mt], bh, acc[mt][nt], 0, 0, 0);
            }
        }
    }
    #undef VLOAD
    #undef ULOAD
    #undef SPLITW

    const int slot = rest & 63;
    #pragma unroll
    for (int nt = 0; nt < 4; ++nt) {
        float rm = -3.4e38f;
        #pragma unroll
        for (int mt = 0; mt < 4; ++mt)
            rm = fmaxf(rm, fmaxf(fmaxf(acc[mt][nt][0], acc[mt][nt][1]),
                                 fmaxf(acc[mt][nt][2], acc[mt][nt][3])));
        rm = fmaxf(rm, __shfl_xor(rm, 16, 64));
        rm = fmaxf(rm, __shfl_xor(rm, 32, 64));
        if (quad == 0) {
            const int col = w * 64 + nt * 16 + l15;
            part[((size_t)cell * 64 + slot) * 256 + col] = rm + hb[col];
        }
    }
}

// ---------------------------------------------------------------------------
// Kernel 6: reduce 64 partial maxes per cell, final MLP (f32), L2 normalize.
// ---------------------------------------------------------------------------
__global__ __launch_bounds__(256)
void k_final(const float* __restrict__ part,
             const float* __restrict__ lW1, const float* __restrict__ lb1,
             const float* __restrict__ lW2, const float* __restrict__ lb2,
             float* __restrict__ out)
{
    __shared__ float pooled[256];
    __shared__ float hid[256];
    __shared__ float red[4];

    const int b = blockIdx.x;
    const int t = threadIdx.x;

    float m = -3.4e38f;
    for (int s = 0; s < 64; ++s)
        m = fmaxf(m, part[((size_t)b * 64 + s) * 256 + t]);
    pooled[t] = m;
    __syncthreads();

    float h = lb1[t];
    for (int k = 0; k < 256; k += 4) {
        #pragma unroll
        for (int kk = 0; kk < 4; ++kk)
            h += pooled[k + kk] * lW1[(k + kk) * 256 + t];
    }
    hid[t] = fmaxf(h, 0.f);
    __syncthreads();

    float o = lb2[t];
    for (int k = 0; k < 256; k += 4) {
        #pragma unroll
        for (int kk = 0; kk < 4; ++kk)
            o += hid[k + kk] * lW2[(k + kk) * 256 + t];
    }

    float ss = o * o;
    #pragma unroll
    for (int s = 32; s > 0; s >>= 1) ss += __shfl_down(ss, s, 64);
    if ((t & 63) == 0) red[t >> 6] = ss;
    __syncthreads();
    const float tot = red[0] + red[1] + red[2] + red[3];
    const float rn = 1.f / fmaxf(sqrtf(tot), 1e-12f);
    out[b * 256 + t] = o * rn;
}

// ---------------------------------------------------------------------------
extern "C" void kernel_launch(void* const* d_in, const int* in_sizes, int n_in,
                              void* d_out, int out_size, void* d_ws, size_t ws_size,
                              hipStream_t stream)
{
    (void)n_in; (void)out_size; (void)ws_size;

    const float* class_table = (const float*)d_in[0];
    const float* cW1 = (const float*)d_in[1];
    const float* cb1 = (const float*)d_in[2];
    const float* cW2 = (const float*)d_in[3];
    const float* cb2 = (const float*)d_in[4];
    const float* pW1 = (const float*)d_in[5];
    const float* pb1 = (const float*)d_in[6];
    const float* pW2 = (const float*)d_in[7];
    const float* pb2 = (const float*)d_in[8];
    const float* mW  = (const float*)d_in[9];
    const float* mb  = (const float*)d_in[10];
    const float* gW1 = (const float*)d_in[11];
    const float* gb1 = (const float*)d_in[12];
    const float* g_gamma = (const float*)d_in[13];
    const float* g_beta  = (const float*)d_in[14];
    const float* gW2 = (const float*)d_in[15];
    const float* gb2 = (const float*)d_in[16];
    const float* lW1 = (const float*)d_in[17];
    const float* lb1 = (const float*)d_in[18];
    const float* lW2 = (const float*)d_in[19];
    const float* lb2 = (const float*)d_in[20];
    const float* positions = (const float*)d_in[21];
    const float* colors    = (const float*)d_in[22];
    const int*  cls        = (const int*)d_in[23];

    const int cstride = (in_sizes[23] == 2 * NTOT) ? 2 : 1;

    // workspace layout (bytes), total ~174 MB (ws_size ~268 MB).
    char* base = (char*)d_ws;
    float*   part   = (float*)(base + 0);               //   4,194,304
    ushort*  Wdh    = (ushort*)(base + 4194304);
    ushort*  Wdl    = (ushort*)(base + 4325376);
    ushort*  Wbh    = (ushort*)(base + 4456448);
    ushort*  Wbl    = (ushort*)(base + 4587520);
    ushort*  g2h    = (ushort*)(base + 4718592);
    ushort*  g2l    = (ushort*)(base + 4849664);
    float*   hb     = (float*)(base + 4980736);
    ushort*  cW2Th  = (ushort*)(base + 4981760);
    ushort*  cW2Tl  = (ushort*)(base + 5014528);
    ushort*  pW2Th  = (ushort*)(base + 5047296);
    ushort*  pW2Tl  = (ushort*)(base + 5080064);
    ushort*  WcTh   = (ushort*)(base + 5112832);
    ushort*  WcTl   = (ushort*)(base + 5145600);
    ushort*  WpTh   = (ushort*)(base + 5178368);
    ushort*  WpTl   = (ushort*)(base + 5211136);
    float*   classMn= (float*)(base + 5243904);
    float*   cbM    = (float*)(base + 5275648);
    float*   pbM    = (float*)(base + 5276672);
    int*     nidx   = (int*)(base + 5277696);           //   1,048,576
    float*   sqn    = (float*)(base + 6326272);         //     131,072
    ushort*  ehi    = (ushort*)(base + 6457344);        //  16,777,216
    ushort*  elo    = (ushort*)(base + 23234560);       //  16,777,216
    float*   dist   = (float*)(base + 40011776);        //  67,108,864
    float*   v      = (float*)(base + 107120640);       //  33,554,432
    float*   u      = (float*)(base + 140675072);       //  33,554,432
    float* out = (float*)d_out;

    k_cvt<<<897, 256, 0, stream>>>(gW1, gW2, g_gamma, g_beta, gb2, cW2, pW2,
                                   Wdh, Wdl, Wbh, Wbl, g2h, g2l, hb,
                                   cW2Th, cW2Tl, pW2Th, pW2Tl);
    k_fold<<<130, 256, 0, stream>>>(cW2, pW2, cb2, pb2, mW,
                                    WcTh, WcTl, WpTh, WpTl, cbM, pbM);
    k_cls<<<31, 256, 0, stream>>>(class_table, mW, classMn);

    k_embed<<<NTOT / 16, 256, 0, stream>>>(classMn, cW1, cb1, cb2, pW1, pb1, pb2,
                                           mb, cW2Th, cW2Tl, pW2Th, pW2Tl,
                                           WcTh, WcTl, WpTh, WpTl, cbM, pbM,
                                           positions, colors, cls, cstride,
                                           ehi, elo, sqn);
    k_gram<<<NB * 32, 256, 0, stream>>>(ehi, elo, sqn, dist);
    k_select<<<NTOT / 4, 256, 0, stream>>>(dist, nidx);
    k_uv<<<2 * NTOT / 64, 256, 0, stream>>>(ehi, elo, Wdh, Wbh, gb1, u, v);
    k_edge<<<NTOT / 8, 256, 0, stream>>>(u, v, nidx, g2h, hb, part);
    k_final<<<NB, 256, 0, stream>>>(part, lW1, lb1, lW2, lb2, out);
}